// Round 5
// baseline (658.392 us; speedup 1.0000x reference)
//
#include <hip/hip_runtime.h>
#include <cmath>
#include <cstdint>

// ---------------------------------------------------------------------------
// DependencyTreeLSTM (R5).  Lesson history:
//  R1 persistent+grid-barrier: L2 invalidates on 8 XCDs -> 2.8x regression.
//  R2 fused level kernel: grid capped at 256 blocks -> latency-bound.
//  R3 zcell register-direct split-K: 45us x 12, latency-serialized loads.
//  R4 zgemm DMA-staged, BK=32: 42us x 12 -- barely better.  Diagnosis: 20
//     K-steps x vmcnt(0)-drain x 2 barriers with 2.5 blocks/CU = drain-count
//     x latency dominates (30cyc MFMA vs ~700cyc drain per step).
//  R5: BK up.  zgemm BK=128 (5 steps, 24 MFMA/step, 40 KB LDS);
//      wxf  BK=160 (2 steps, 40 MFMA/step, 60 KB LDS).  k-chunk-major LDS
//      layout ([kc][row][8], 16B rows) kept: measured 0 bank conflicts.
// ---------------------------------------------------------------------------

#define NN    4096
#define HH    300
#define KK    8
#define LVLS  12
#define KP    320

typedef __bf16  bf16x8 __attribute__((ext_vector_type(8)));
typedef float   f32x4  __attribute__((ext_vector_type(4)));

#define GAS __attribute__((address_space(1)))
#define LAS __attribute__((address_space(3)))

__device__ __forceinline__ float sigmoidf_(float x) {
    return 1.0f / (1.0f + expf(-x));
}
__device__ __forceinline__ ushort f2bf(float f) {   // f32 -> bf16, RNE
    union { float f; uint32_t u; } v; v.f = f;
    return (ushort)((v.u + 0x7fffu + ((v.u >> 16) & 1u)) >> 16);
}
__device__ __forceinline__ float bf2f(ushort u) {
    union { uint32_t u; float f; } v; v.u = ((uint32_t)u) << 16;
    return v.f;
}

// ---------------------------------------------------------------------------
// Weight packing (bf16, padded) + X staging, one dispatch.
//   blocks [0, 3207):      pack  (WfP, Uf, Wz, BZ, Bwf, BUF)
//   blocks [3207, 18567):  stage (X for all 12 levels)
// ---------------------------------------------------------------------------
__global__ __launch_bounds__(256)
void pack_and_stage(
    const float* __restrict__ wi, const float* __restrict__ bwi,
    const float* __restrict__ ui, const float* __restrict__ bui,
    const float* __restrict__ wf, const float* __restrict__ bwf,
    const float* __restrict__ uf, const float* __restrict__ buf_,
    const float* __restrict__ wo, const float* __restrict__ bwo,
    const float* __restrict__ uo, const float* __restrict__ buo,
    const float* __restrict__ wu, const float* __restrict__ bwu,
    const float* __restrict__ uu, const float* __restrict__ buu,
    ushort* __restrict__ WfP, ushort* __restrict__ Uf, ushort* __restrict__ Wz,
    float* __restrict__ BZ, float* __restrict__ Bwf, float* __restrict__ BUF,
    const int* __restrict__ word_ids, const float* __restrict__ emb,
    ushort* __restrict__ X)
{
    const int b = blockIdx.x;
    if (b >= 3207) {                                     // ---- stage part
        int idx = (b - 3207) * 256 + threadIdx.x;        // 12*4096*80
        int nl = idx / 80, kc = idx % 80, k = kc * 4;
        ushort4 o;
        if (kc < 75) {
            const float2* p = reinterpret_cast<const float2*>(
                emb + (size_t)word_ids[nl] * 300 + k);
            float2 v0 = p[0], v1 = p[1];
            o.x = f2bf(v0.x); o.y = f2bf(v0.y); o.z = f2bf(v1.x); o.w = f2bf(v1.y);
        } else {
            o.x = o.y = o.z = o.w = 0;
        }
        *reinterpret_cast<ushort4*>(X + (size_t)nl * KP + k) = o;
        return;
    }
    int t = b * 256 + threadIdx.x;                       // ---- pack part
    if (t < 102400) {                                    // WfP
        int r = t / KP, k = t % KP;
        WfP[t] = f2bf((r < 300 && k < 300) ? wf[r * 300 + k] : 0.f);
    } else if (t < 204800) {                             // Uf
        int x = t - 102400, r = x / KP, k = x % KP;
        Uf[x] = f2bf((r < 300 && k < 300) ? uf[r * 300 + k] : 0.f);
    } else if (t < 819200) {                             // Wz [3][320][640]
        int x = t - 204800;
        int g = x / 204800, rem = x % 204800;
        int r = rem / 640, k = rem % 640;
        const float* W = (g == 0) ? wi : (g == 1) ? wo : wu;
        const float* U = (g == 0) ? ui : (g == 1) ? uo : uu;
        float v = 0.f;
        if (r < 300) {
            if (k < 320) { if (k < 300) v = W[r * 300 + k]; }
            else         { int kk = k - 320; if (kk < 300) v = U[r * 300 + kk]; }
        }
        Wz[x] = f2bf(v);
    } else if (t < 820160) {                             // BZ [3][320]
        int x = t - 819200, g = x / KP, r = x % KP;
        const float* bw = (g == 0) ? bwi : (g == 1) ? bwo : bwu;
        const float* bu = (g == 0) ? bui : (g == 1) ? buo : buu;
        BZ[x] = (r < 300) ? bw[r] + bu[r] : 0.f;
    } else if (t < 820480) {                             // Bwf
        int r = t - 820160;
        Bwf[r] = (r < 300) ? bwf[r] : 0.f;
    } else if (t < 820800) {                             // BUF
        int r = t - 820480;
        BUF[r] = (r < 300) ? buf_[r] : 0.f;
    }
}

// ---------------------------------------------------------------------------
// WXF_all = X_all[49152][320] @ w_f^T + b_wf -> bf16 [49152][320].
// Grid 1920, 256 thr, BK=160 -> 2 K-steps (2 vmcnt drains instead of 10).
// LDS 60 KB (As 40 + Bs 20), k-chunk-major 16B-row layout (0 conflicts).
// ---------------------------------------------------------------------------
__global__ __launch_bounds__(256)
void wxf_all_kernel(const ushort* __restrict__ Xall, const ushort* __restrict__ WfP,
                    const float* __restrict__ Bwf, ushort* __restrict__ WXFall)
{
    __shared__ __attribute__((aligned(16))) ushort As[20][128][8];   // 40 KB
    __shared__ __attribute__((aligned(16))) ushort Bs[20][64][8];    // 20 KB

    const int b  = blockIdx.x;
    const int bj = (b % 8) * 240 + b / 8;         // bijective (1920 % 8 == 0)
    const int m0 = (bj / 5) * 128, n0 = (bj % 5) * 64;

    const int t = threadIdx.x, l = t & 63, w = t >> 6;
    const int m_off = (w >> 1) * 64, n_off = (w & 1) * 32;
    const int kq = l >> 4, lr = l & 15;

    f32x4 acc[4][2] = {};

    for (int s = 0; s < 2; ++s) {
        #pragma unroll
        for (int c = 0; c < 10; ++c) {            // A: 2560 slots, 10/thread
            const int i = t + 256 * c;
            const int kb = i >> 7, row = i & 127;
            const ushort* src = Xall + (size_t)(m0 + row) * KP
                                     + (size_t)(s * 20 + kb) * 8;
            __builtin_amdgcn_global_load_lds((const GAS void*)src,
                (LAS void*)&As[kb][row][0], 16, 0, 0);
        }
        #pragma unroll
        for (int c = 0; c < 5; ++c) {             // B: 1280 slots, 5/thread
            const int i = t + 256 * c;
            const int kb = i >> 6, row = i & 63;
            const ushort* src = WfP + (size_t)(n0 + row) * KP
                                    + (size_t)(s * 20 + kb) * 8;
            __builtin_amdgcn_global_load_lds((const GAS void*)src,
                (LAS void*)&Bs[kb][row][0], 16, 0, 0);
        }
        __syncthreads();

        #pragma unroll
        for (int kk = 0; kk < 5; ++kk) {
            const int kc = kk * 4 + kq;
            bf16x8 af[4], bfr[2];
            #pragma unroll
            for (int mi = 0; mi < 4; ++mi)
                af[mi] = *reinterpret_cast<const bf16x8*>(
                    &As[kc][m_off + mi * 16 + lr][0]);
            #pragma unroll
            for (int ni = 0; ni < 2; ++ni)
                bfr[ni] = *reinterpret_cast<const bf16x8*>(
                    &Bs[kc][n_off + ni * 16 + lr][0]);
            #pragma unroll
            for (int mi = 0; mi < 4; ++mi)
                #pragma unroll
                for (int ni = 0; ni < 2; ++ni)
                    acc[mi][ni] = __builtin_amdgcn_mfma_f32_16x16x32_bf16(
                        af[mi], bfr[ni], acc[mi][ni], 0, 0, 0);
        }
        __syncthreads();
    }

    const int col = l & 15, r0 = (l >> 4) * 4;
    #pragma unroll
    for (int mi = 0; mi < 4; ++mi) {
        #pragma unroll
        for (int ni = 0; ni < 2; ++ni) {
            const int gn = n0 + n_off + ni * 16 + col;
            const float bb = Bwf[gn];
            #pragma unroll
            for (int r = 0; r < 4; ++r) {
                const int gm = m0 + m_off + mi * 16 + r0 + r;
                WXFall[(size_t)gm * KP + gn] = f2bf(acc[mi][ni][r] + bb);
            }
        }
    }
}

__device__ __forceinline__ int swz640(int b) { return (b % 8) * 80 + b / 8; }

// ---------------------------------------------------------------------------
// FP = Hbf @ u_f^T + b_uf  (bf16 out, [4096][320]).  Grid 640 x 128 thr.
// Register-direct: lane (kq,lr) loads its own 16B fragments; no LDS/barriers.
// ---------------------------------------------------------------------------
__global__ __launch_bounds__(128)
void fp_kernel(const ushort* __restrict__ Hbf, const ushort* __restrict__ Uf,
               const float* __restrict__ BUF, ushort* __restrict__ FP)
{
    const int bj = swz640((int)blockIdx.x);
    const int m0 = (bj / 10) * 64, n0 = (bj % 10) * 32;
    const int t = threadIdx.x, w = t >> 6, l = t & 63;
    const int kq = l >> 4, lr = l & 15, m_off = w * 32;

    f32x4 acc[2][2] = {};
    #pragma unroll
    for (int s = 0; s < 10; ++s) {
        const int kc = s * 4 + kq;
        bf16x8 af[2], bfr[2];
        #pragma unroll
        for (int mi = 0; mi < 2; ++mi)
            af[mi] = *reinterpret_cast<const bf16x8*>(
                Hbf + (size_t)(m0 + m_off + mi * 16 + lr) * KP + (size_t)kc * 8);
        #pragma unroll
        for (int ni = 0; ni < 2; ++ni)
            bfr[ni] = *reinterpret_cast<const bf16x8*>(
                Uf + (size_t)(n0 + ni * 16 + lr) * KP + (size_t)kc * 8);
        #pragma unroll
        for (int mi = 0; mi < 2; ++mi)
            #pragma unroll
            for (int ni = 0; ni < 2; ++ni)
                acc[mi][ni] = __builtin_amdgcn_mfma_f32_16x16x32_bf16(
                    af[mi], bfr[ni], acc[mi][ni], 0, 0, 0);
    }

    const int col = l & 15, r0 = (l >> 4) * 4;
    #pragma unroll
    for (int mi = 0; mi < 2; ++mi) {
        #pragma unroll
        for (int ni = 0; ni < 2; ++ni) {
            const int gn = n0 + ni * 16 + col;
            const float bb = BUF[gn];
            #pragma unroll
            for (int r = 0; r < 4; ++r) {
                const int gm = m0 + m_off + mi * 16 + r0 + r;
                FP[(size_t)gm * KP + gn] = f2bf(acc[mi][ni][r] + bb);
            }
        }
    }
}

// ---------------------------------------------------------------------------
// Child gather + masked sums.  4 nodes/block, vectorized, branchless
// prefetched loads (MLP); math stays masked.
// ---------------------------------------------------------------------------
__global__ __launch_bounds__(320)
void reduce_kernel(const ushort* __restrict__ Hbf, const float* __restrict__ Cst,
                   const ushort* __restrict__ FP, const ushort* __restrict__ WXF,
                   const int* __restrict__ cidx, const float* __restrict__ cmask,
                   ushort* __restrict__ HT, float* __restrict__ SC)
{
    const int x = threadIdx.x;          // 0..79
    const int ty = threadIdx.y;         // 0..3
    const int n = blockIdx.x * 4 + ty;
    __shared__ int   ch[4][KK];
    __shared__ float mk[4][KK];
    if (x < KK) {
        ch[ty][x] = cidx[n * KK + x];
        mk[ty][x] = cmask[n * KK + x];
    }
    __syncthreads();
    if (x >= 75) return;
    const int h = x * 4;

    ushort4 hu[KK]; ushort4 fu[KK]; float4 cv[KK];
    #pragma unroll
    for (int k = 0; k < KK; ++k) {
        const size_t cr = (size_t)ch[ty][k];
        hu[k] = *reinterpret_cast<const ushort4*>(&Hbf[cr * KP + h]);
        fu[k] = *reinterpret_cast<const ushort4*>(&FP [cr * KP + h]);
        cv[k] = *reinterpret_cast<const float4*>(&Cst[cr * HH + h]);
    }

    ushort4 wxu = *reinterpret_cast<const ushort4*>(&WXF[(size_t)n * KP + h]);
    const float wx0 = bf2f(wxu.x), wx1 = bf2f(wxu.y),
                wx2 = bf2f(wxu.z), wx3 = bf2f(wxu.w);
    float ht0 = 0.f, ht1 = 0.f, ht2 = 0.f, ht3 = 0.f;
    float sc0 = 0.f, sc1 = 0.f, sc2 = 0.f, sc3 = 0.f;

    #pragma unroll
    for (int k = 0; k < KK; ++k) {
        const float m = mk[ty][k];
        if (m != 0.f) {
            ht0 += m * bf2f(hu[k].x); ht1 += m * bf2f(hu[k].y);
            ht2 += m * bf2f(hu[k].z); ht3 += m * bf2f(hu[k].w);
            sc0 += m * sigmoidf_(wx0 + bf2f(fu[k].x)) * cv[k].x;
            sc1 += m * sigmoidf_(wx1 + bf2f(fu[k].y)) * cv[k].y;
            sc2 += m * sigmoidf_(wx2 + bf2f(fu[k].z)) * cv[k].z;
            sc3 += m * sigmoidf_(wx3 + bf2f(fu[k].w)) * cv[k].w;
        }
    }
    ushort4 ho; ho.x = f2bf(ht0); ho.y = f2bf(ht1); ho.z = f2bf(ht2); ho.w = f2bf(ht3);
    *reinterpret_cast<ushort4*>(&HT[(size_t)n * KP + h]) = ho;
    float4 so; so.x = sc0; so.y = sc1; so.z = sc2; so.w = sc3;
    *reinterpret_cast<float4*>(&SC[(size_t)n * KP + h]) = so;
}

// ---------------------------------------------------------------------------
// zgemm: gates GEMM + fused cell epilogue.  BK=128 -> 5 K-steps (vs 20).
// Tile 64 rows x 32 j x 3 gates; grid 640, 256 thr (4 waves 2x2).
// LDS 40 KB (As 16 + Bs 24), k-chunk-major layout.  K=640 concat [X|HT]
// splits at global k-chunk 40 (per-slot address select; step 2 straddles).
// ---------------------------------------------------------------------------
__global__ __launch_bounds__(256)
void zgemm(const ushort* __restrict__ X, const ushort* __restrict__ HT,
           const ushort* __restrict__ Wz, const float* __restrict__ BZ,
           const float* __restrict__ SC,
           float* __restrict__ cdst, ushort* __restrict__ Hb,
           float* __restrict__ hdst)
{
    __shared__ __attribute__((aligned(16))) ushort As[16][64][8];    // 16 KB
    __shared__ __attribute__((aligned(16))) ushort Bs[3][16][32][8]; // 24 KB

    const int b  = blockIdx.x;
    const int bj = (b % 8) * 80 + b / 8;          // bijective (640 % 8 == 0)
    const int m0 = (bj / 10) * 64, j0 = (bj % 10) * 32;

    const int t = threadIdx.x, w = t >> 6, l = t & 63;
    const int kq = l >> 4, lr = l & 15;
    const int m_off = (w >> 1) * 32, j_off = (w & 1) * 16;

    const int arow = t & 63, akb0 = t >> 6;       // A: kb = akb0 + 4c

    f32x4 acc[3][2] = {};

    for (int s = 0; s < 5; ++s) {
        #pragma unroll
        for (int c = 0; c < 4; ++c) {             // A: 1024 slots, 4/thread
            const int kb  = akb0 + c * 4;
            const int kcg = s * 16 + kb;          // global concat k-chunk
            const ushort* src = (kcg < 40)
                ? (X  + (size_t)(m0 + arow) * KP + (size_t)kcg * 8)
                : (HT + (size_t)(m0 + arow) * KP + (size_t)(kcg - 40) * 8);
            __builtin_amdgcn_global_load_lds((const GAS void*)src,
                (LAS void*)&As[kb][arow][0], 16, 0, 0);
        }
        #pragma unroll
        for (int c = 0; c < 6; ++c) {             // B: 1536 slots, 6/thread
            const int i = t + 256 * c;
            const int g = i >> 9, rem = i & 511;
            const int kb = rem >> 5, row = rem & 31;
            const ushort* src = Wz + ((size_t)g * KP + j0 + row) * 640
                                   + (size_t)(s * 16 + kb) * 8;
            __builtin_amdgcn_global_load_lds((const GAS void*)src,
                (LAS void*)&Bs[g][kb][row][0], 16, 0, 0);
        }
        __syncthreads();

        #pragma unroll
        for (int kk = 0; kk < 4; ++kk) {
            const int kc = kk * 4 + kq;
            bf16x8 af[2], bfr[3];
            #pragma unroll
            for (int mi = 0; mi < 2; ++mi)
                af[mi] = *reinterpret_cast<const bf16x8*>(
                    &As[kc][m_off + mi * 16 + lr][0]);
            #pragma unroll
            for (int g = 0; g < 3; ++g)
                bfr[g] = *reinterpret_cast<const bf16x8*>(
                    &Bs[g][kc][j_off + lr][0]);
            #pragma unroll
            for (int g = 0; g < 3; ++g)
                #pragma unroll
                for (int mi = 0; mi < 2; ++mi)
                    acc[g][mi] = __builtin_amdgcn_mfma_f32_16x16x32_bf16(
                        af[mi], bfr[g], acc[g][mi], 0, 0, 0);
        }
        __syncthreads();
    }

    // ---- fused cell epilogue (all 3 gates present per element) ----------
    const int col = l & 15, r0 = (l >> 4) * 4;
    const int gn = j0 + j_off + col;
    if (gn < 300) {
        const float bi_ = BZ[gn], bo_ = BZ[KP + gn], bu_ = BZ[2 * KP + gn];
        #pragma unroll
        for (int mi = 0; mi < 2; ++mi) {
            #pragma unroll
            for (int r = 0; r < 4; ++r) {
                const int gm = m0 + m_off + mi * 16 + r0 + r;
                const float sc = SC[(size_t)gm * KP + gn];
                const float ig = sigmoidf_(acc[0][mi][r] + bi_);
                const float og = sigmoidf_(acc[1][mi][r] + bo_);
                const float ug = tanhf   (acc[2][mi][r] + bu_);
                const float c  = ig * ug + sc;
                const float hv = og * tanhf(c);
                cdst[(size_t)gm * HH + gn] = c;
                Hb  [(size_t)gm * KP + gn] = f2bf(hv);
                if (hdst) hdst[(size_t)gm * HH + gn] = hv;
            }
        }
    }
}

// ---------------------------------------------------------------------------
extern "C" void kernel_launch(void* const* d_in, const int* in_sizes, int n_in,
                              void* d_out, int out_size, void* d_ws, size_t ws_size,
                              hipStream_t stream)
{
    const int*   word_ids   = (const int*)  d_in[0];
    const int*   child_idx  = (const int*)  d_in[1];
    const float* child_mask = (const float*)d_in[2];
    const float* emb        = (const float*)d_in[3];
    const float* w_i  = (const float*)d_in[4];  const float* b_wi = (const float*)d_in[5];
    const float* u_i  = (const float*)d_in[6];  const float* b_ui = (const float*)d_in[7];
    const float* w_f  = (const float*)d_in[8];  const float* b_wf = (const float*)d_in[9];
    const float* u_f  = (const float*)d_in[10]; const float* b_uf = (const float*)d_in[11];
    const float* w_o  = (const float*)d_in[12]; const float* b_wo = (const float*)d_in[13];
    const float* u_o  = (const float*)d_in[14]; const float* b_uo = (const float*)d_in[15];
    const float* w_u  = (const float*)d_in[16]; const float* b_wu = (const float*)d_in[17];
    const float* u_u  = (const float*)d_in[18]; const float* b_uu = (const float*)d_in[19];

    uint8_t* ws = (uint8_t*)d_ws;
    size_t off = 0;
    auto alloc = [&](size_t bytes) {
        uint8_t* p = ws + off;
        off += (bytes + 255) & ~(size_t)255;
        return p;
    };
    ushort* WfP   = (ushort*)alloc((size_t)KP * KP * 2);
    ushort* Uf    = (ushort*)alloc((size_t)KP * KP * 2);
    ushort* Wz    = (ushort*)alloc((size_t)3 * KP * 640 * 2);
    ushort* Xall  = (ushort*)alloc((size_t)LVLS * NN * KP * 2);
    ushort* WXFall= (ushort*)alloc((size_t)LVLS * NN * KP * 2);
    ushort* FPbf  = (ushort*)alloc((size_t)NN * KP * 2);
    ushort* HTbf  = (ushort*)alloc((size_t)NN * KP * 2);
    ushort* Hbf   = (ushort*)alloc((size_t)NN * KP * 2);
    float*  SCb   = (float*) alloc((size_t)NN * KP * 4);
    float*  C0    = (float*) alloc((size_t)NN * HH * 4);
    float*  BZ    = (float*) alloc(3 * KP * 4);
    float*  Bwf   = (float*) alloc(KP * 4);
    float*  BUFb  = (float*) alloc(KP * 4);

    pack_and_stage<<<18567, 256, 0, stream>>>(
        w_i, b_wi, u_i, b_ui, w_f, b_wf, u_f, b_uf,
        w_o, b_wo, u_o, b_uo, w_u, b_wu, u_u, b_uu,
        WfP, Uf, Wz, BZ, Bwf, BUFb,
        word_ids, emb, Xall);
    wxf_all_kernel<<<1920, 256, 0, stream>>>(Xall, WfP, Bwf, WXFall);

    float* h_final = (float*)d_out;
    float* c_final = (float*)d_out + (size_t)NN * HH;

    for (int lev = 0; lev < LVLS; ++lev) {
        const int*    cidx  = child_idx  + (size_t)lev * NN * KK;
        const float*  cmask = child_mask + (size_t)lev * NN * KK;
        const ushort* Xlev  = Xall   + (size_t)lev * NN * KP;
        const ushort* WXFlev= WXFall + (size_t)lev * NN * KP;
        const bool last = (lev == LVLS - 1);
        float* cdst = last ? c_final : C0;
        float* hdst = last ? h_final : nullptr;

        if (lev > 0)
            fp_kernel<<<640, 128, 0, stream>>>(Hbf, Uf, BUFb, FPbf);
        reduce_kernel<<<1024, dim3(80, 4), 0, stream>>>(
            Hbf, C0, FPbf, WXFlev, cidx, cmask, HTbf, SCb);
        zgemm<<<640, 256, 0, stream>>>(
            Xlev, HTbf, Wz, BZ, SCb, cdst, Hbf, hdst);
    }
}

// Round 6
// 652.802 us; speedup vs baseline: 1.0086x; 1.0086x over previous
//
#include <hip/hip_runtime.h>
#include <cmath>
#include <cstdint>

// ---------------------------------------------------------------------------
// DependencyTreeLSTM (R6).  Lesson history:
//  R1 persistent+grid-barrier: L2 invalidates on 8 XCDs -> 2.8x regression.
//  R2 fused level kernel: grid capped at 256 blocks -> latency-bound.
//  R3 zcell register-direct: 45us x12, latency-serialized loads.
//  R4 zgemm DMA BK=32: 42us.  R5 BK=128/160: 44us -- drain COUNT irrelevant;
//     each step's LDS fill is fully exposed (issue->vmcnt(0)->bar->compute).
//  R6: T3+T4 pipeline (m201 pattern): double-buffered LDS, issue step s+1
//      BEFORE computing step s, counted vmcnt(loads-in-flight) + raw
//      s_barrier -- never drain to 0 in the loop.  zgemm BK=64 (10 steps,
//      40 KB dbuf, 4 blk/CU); wxf BK=64 (5 steps, 48 KB dbuf, 3 blk/CU).
//      Math, tiling, epilogues, other kernels: unchanged from R5.
// ---------------------------------------------------------------------------

#define NN    4096
#define HH    300
#define KK    8
#define LVLS  12
#define KP    320

typedef __bf16  bf16x8 __attribute__((ext_vector_type(8)));
typedef float   f32x4  __attribute__((ext_vector_type(4)));

#define GAS __attribute__((address_space(1)))
#define LAS __attribute__((address_space(3)))

__device__ __forceinline__ float sigmoidf_(float x) {
    return 1.0f / (1.0f + expf(-x));
}
__device__ __forceinline__ ushort f2bf(float f) {   // f32 -> bf16, RNE
    union { float f; uint32_t u; } v; v.f = f;
    return (ushort)((v.u + 0x7fffu + ((v.u >> 16) & 1u)) >> 16);
}
__device__ __forceinline__ float bf2f(ushort u) {
    union { uint32_t u; float f; } v; v.u = ((uint32_t)u) << 16;
    return v.f;
}

// ---------------------------------------------------------------------------
// Weight packing (bf16, padded) + X staging, one dispatch.
// ---------------------------------------------------------------------------
__global__ __launch_bounds__(256)
void pack_and_stage(
    const float* __restrict__ wi, const float* __restrict__ bwi,
    const float* __restrict__ ui, const float* __restrict__ bui,
    const float* __restrict__ wf, const float* __restrict__ bwf,
    const float* __restrict__ uf, const float* __restrict__ buf_,
    const float* __restrict__ wo, const float* __restrict__ bwo,
    const float* __restrict__ uo, const float* __restrict__ buo,
    const float* __restrict__ wu, const float* __restrict__ bwu,
    const float* __restrict__ uu, const float* __restrict__ buu,
    ushort* __restrict__ WfP, ushort* __restrict__ Uf, ushort* __restrict__ Wz,
    float* __restrict__ BZ, float* __restrict__ Bwf, float* __restrict__ BUF,
    const int* __restrict__ word_ids, const float* __restrict__ emb,
    ushort* __restrict__ X)
{
    const int b = blockIdx.x;
    if (b >= 3207) {                                     // ---- stage part
        int idx = (b - 3207) * 256 + threadIdx.x;        // 12*4096*80
        int nl = idx / 80, kc = idx % 80, k = kc * 4;
        ushort4 o;
        if (kc < 75) {
            const float2* p = reinterpret_cast<const float2*>(
                emb + (size_t)word_ids[nl] * 300 + k);
            float2 v0 = p[0], v1 = p[1];
            o.x = f2bf(v0.x); o.y = f2bf(v0.y); o.z = f2bf(v1.x); o.w = f2bf(v1.y);
        } else {
            o.x = o.y = o.z = o.w = 0;
        }
        *reinterpret_cast<ushort4*>(X + (size_t)nl * KP + k) = o;
        return;
    }
    int t = b * 256 + threadIdx.x;                       // ---- pack part
    if (t < 102400) {                                    // WfP
        int r = t / KP, k = t % KP;
        WfP[t] = f2bf((r < 300 && k < 300) ? wf[r * 300 + k] : 0.f);
    } else if (t < 204800) {                             // Uf
        int x = t - 102400, r = x / KP, k = x % KP;
        Uf[x] = f2bf((r < 300 && k < 300) ? uf[r * 300 + k] : 0.f);
    } else if (t < 819200) {                             // Wz [3][320][640]
        int x = t - 204800;
        int g = x / 204800, rem = x % 204800;
        int r = rem / 640, k = rem % 640;
        const float* W = (g == 0) ? wi : (g == 1) ? wo : wu;
        const float* U = (g == 0) ? ui : (g == 1) ? uo : uu;
        float v = 0.f;
        if (r < 300) {
            if (k < 320) { if (k < 300) v = W[r * 300 + k]; }
            else         { int kk = k - 320; if (kk < 300) v = U[r * 300 + kk]; }
        }
        Wz[x] = f2bf(v);
    } else if (t < 820160) {                             // BZ [3][320]
        int x = t - 819200, g = x / KP, r = x % KP;
        const float* bw = (g == 0) ? bwi : (g == 1) ? bwo : bwu;
        const float* bu = (g == 0) ? bui : (g == 1) ? buo : buu;
        BZ[x] = (r < 300) ? bw[r] + bu[r] : 0.f;
    } else if (t < 820480) {                             // Bwf
        int r = t - 820160;
        Bwf[r] = (r < 300) ? bwf[r] : 0.f;
    } else if (t < 820800) {                             // BUF
        int r = t - 820480;
        BUF[r] = (r < 300) ? buf_[r] : 0.f;
    }
}

// ---------------------------------------------------------------------------
// WXF_all = X_all[49152][320] @ w_f^T + b_wf -> bf16 [49152][320].
// Grid 1920, 256 thr.  T3+T4 pipeline: BK=64, 5 steps, double-buffered LDS
// (48 KB), counted vmcnt(6) + raw s_barrier; loads never drain in-loop.
// ---------------------------------------------------------------------------
__global__ __launch_bounds__(256)
void wxf_all_kernel(const ushort* __restrict__ Xall, const ushort* __restrict__ WfP,
                    const float* __restrict__ Bwf, ushort* __restrict__ WXFall)
{
    __shared__ __attribute__((aligned(16))) ushort As[2][8][128][8];  // 32 KB
    __shared__ __attribute__((aligned(16))) ushort Bs[2][8][64][8];   // 16 KB

    const int b  = blockIdx.x;
    const int bj = (b % 8) * 240 + b / 8;         // bijective (1920 % 8 == 0)
    const int m0 = (bj / 5) * 128, n0 = (bj % 5) * 64;

    const int t = threadIdx.x, l = t & 63, w = t >> 6;
    const int m_off = (w >> 1) * 64, n_off = (w & 1) * 32;
    const int kq = l >> 4, lr = l & 15;

    f32x4 acc[4][2] = {};

    auto STAGE = [&](int buf, int s) {
        #pragma unroll
        for (int c = 0; c < 4; ++c) {             // A: 1024 slots, 4/thread
            const int slot = t + 256 * c;
            const int kb = slot >> 7, row = slot & 127;
            const ushort* src = Xall + (size_t)(m0 + row) * KP
                                     + (size_t)(s * 8 + kb) * 8;
            __builtin_amdgcn_global_load_lds((const GAS void*)src,
                (LAS void*)&As[buf][kb][row][0], 16, 0, 0);
        }
        #pragma unroll
        for (int c = 0; c < 2; ++c) {             // B: 512 slots, 2/thread
            const int slot = t + 256 * c;
            const int kb = slot >> 6, row = slot & 63;
            const ushort* src = WfP + (size_t)(n0 + row) * KP
                                    + (size_t)(s * 8 + kb) * 8;
            __builtin_amdgcn_global_load_lds((const GAS void*)src,
                (LAS void*)&Bs[buf][kb][row][0], 16, 0, 0);
        }
    };
    auto COMPUTE = [&](int buf) {
        #pragma unroll
        for (int kk = 0; kk < 2; ++kk) {
            const int kc = kk * 4 + kq;
            bf16x8 af[4], bfr[2];
            #pragma unroll
            for (int mi = 0; mi < 4; ++mi)
                af[mi] = *reinterpret_cast<const bf16x8*>(
                    &As[buf][kc][m_off + mi * 16 + lr][0]);
            #pragma unroll
            for (int ni = 0; ni < 2; ++ni)
                bfr[ni] = *reinterpret_cast<const bf16x8*>(
                    &Bs[buf][kc][n_off + ni * 16 + lr][0]);
            #pragma unroll
            for (int mi = 0; mi < 4; ++mi)
                #pragma unroll
                for (int ni = 0; ni < 2; ++ni)
                    acc[mi][ni] = __builtin_amdgcn_mfma_f32_16x16x32_bf16(
                        af[mi], bfr[ni], acc[mi][ni], 0, 0, 0);
        }
    };

    STAGE(0, 0);
    #pragma unroll
    for (int s = 0; s < 4; ++s) {
        STAGE((s + 1) & 1, s + 1);                // 6 loads in flight
        asm volatile("s_waitcnt vmcnt(6)" ::: "memory");
        __builtin_amdgcn_s_barrier();
        COMPUTE(s & 1);
        __builtin_amdgcn_s_barrier();             // readers done before restage
    }
    asm volatile("s_waitcnt vmcnt(0)" ::: "memory");
    __builtin_amdgcn_s_barrier();
    COMPUTE(0);                                   // step 4 -> buf 0

    const int col = l & 15, r0 = (l >> 4) * 4;
    #pragma unroll
    for (int mi = 0; mi < 4; ++mi) {
        #pragma unroll
        for (int ni = 0; ni < 2; ++ni) {
            const int gn = n0 + n_off + ni * 16 + col;
            const float bb = Bwf[gn];
            #pragma unroll
            for (int r = 0; r < 4; ++r) {
                const int gm = m0 + m_off + mi * 16 + r0 + r;
                WXFall[(size_t)gm * KP + gn] = f2bf(acc[mi][ni][r] + bb);
            }
        }
    }
}

__device__ __forceinline__ int swz640(int b) { return (b % 8) * 80 + b / 8; }

// ---------------------------------------------------------------------------
// FP = Hbf @ u_f^T + b_uf  (bf16 out, [4096][320]).  Grid 640 x 128 thr.
// Register-direct (fast already, ~3us).
// ---------------------------------------------------------------------------
__global__ __launch_bounds__(128)
void fp_kernel(const ushort* __restrict__ Hbf, const ushort* __restrict__ Uf,
               const float* __restrict__ BUF, ushort* __restrict__ FP)
{
    const int bj = swz640((int)blockIdx.x);
    const int m0 = (bj / 10) * 64, n0 = (bj % 10) * 32;
    const int t = threadIdx.x, w = t >> 6, l = t & 63;
    const int kq = l >> 4, lr = l & 15, m_off = w * 32;

    f32x4 acc[2][2] = {};
    #pragma unroll
    for (int s = 0; s < 10; ++s) {
        const int kc = s * 4 + kq;
        bf16x8 af[2], bfr[2];
        #pragma unroll
        for (int mi = 0; mi < 2; ++mi)
            af[mi] = *reinterpret_cast<const bf16x8*>(
                Hbf + (size_t)(m0 + m_off + mi * 16 + lr) * KP + (size_t)kc * 8);
        #pragma unroll
        for (int ni = 0; ni < 2; ++ni)
            bfr[ni] = *reinterpret_cast<const bf16x8*>(
                Uf + (size_t)(n0 + ni * 16 + lr) * KP + (size_t)kc * 8);
        #pragma unroll
        for (int mi = 0; mi < 2; ++mi)
            #pragma unroll
            for (int ni = 0; ni < 2; ++ni)
                acc[mi][ni] = __builtin_amdgcn_mfma_f32_16x16x32_bf16(
                    af[mi], bfr[ni], acc[mi][ni], 0, 0, 0);
    }

    const int col = l & 15, r0 = (l >> 4) * 4;
    #pragma unroll
    for (int mi = 0; mi < 2; ++mi) {
        #pragma unroll
        for (int ni = 0; ni < 2; ++ni) {
            const int gn = n0 + ni * 16 + col;
            const float bb = BUF[gn];
            #pragma unroll
            for (int r = 0; r < 4; ++r) {
                const int gm = m0 + m_off + mi * 16 + r0 + r;
                FP[(size_t)gm * KP + gn] = f2bf(acc[mi][ni][r] + bb);
            }
        }
    }
}

// ---------------------------------------------------------------------------
// Child gather + masked sums.  4 nodes/block, vectorized, branchless
// prefetched loads (MLP); math stays masked.
// ---------------------------------------------------------------------------
__global__ __launch_bounds__(320)
void reduce_kernel(const ushort* __restrict__ Hbf, const float* __restrict__ Cst,
                   const ushort* __restrict__ FP, const ushort* __restrict__ WXF,
                   const int* __restrict__ cidx, const float* __restrict__ cmask,
                   ushort* __restrict__ HT, float* __restrict__ SC)
{
    const int x = threadIdx.x;          // 0..79
    const int ty = threadIdx.y;         // 0..3
    const int n = blockIdx.x * 4 + ty;
    __shared__ int   ch[4][KK];
    __shared__ float mk[4][KK];
    if (x < KK) {
        ch[ty][x] = cidx[n * KK + x];
        mk[ty][x] = cmask[n * KK + x];
    }
    __syncthreads();
    if (x >= 75) return;
    const int h = x * 4;

    ushort4 hu[KK]; ushort4 fu[KK]; float4 cv[KK];
    #pragma unroll
    for (int k = 0; k < KK; ++k) {
        const size_t cr = (size_t)ch[ty][k];
        hu[k] = *reinterpret_cast<const ushort4*>(&Hbf[cr * KP + h]);
        fu[k] = *reinterpret_cast<const ushort4*>(&FP [cr * KP + h]);
        cv[k] = *reinterpret_cast<const float4*>(&Cst[cr * HH + h]);
    }

    ushort4 wxu = *reinterpret_cast<const ushort4*>(&WXF[(size_t)n * KP + h]);
    const float wx0 = bf2f(wxu.x), wx1 = bf2f(wxu.y),
                wx2 = bf2f(wxu.z), wx3 = bf2f(wxu.w);
    float ht0 = 0.f, ht1 = 0.f, ht2 = 0.f, ht3 = 0.f;
    float sc0 = 0.f, sc1 = 0.f, sc2 = 0.f, sc3 = 0.f;

    #pragma unroll
    for (int k = 0; k < KK; ++k) {
        const float m = mk[ty][k];
        if (m != 0.f) {
            ht0 += m * bf2f(hu[k].x); ht1 += m * bf2f(hu[k].y);
            ht2 += m * bf2f(hu[k].z); ht3 += m * bf2f(hu[k].w);
            sc0 += m * sigmoidf_(wx0 + bf2f(fu[k].x)) * cv[k].x;
            sc1 += m * sigmoidf_(wx1 + bf2f(fu[k].y)) * cv[k].y;
            sc2 += m * sigmoidf_(wx2 + bf2f(fu[k].z)) * cv[k].z;
            sc3 += m * sigmoidf_(wx3 + bf2f(fu[k].w)) * cv[k].w;
        }
    }
    ushort4 ho; ho.x = f2bf(ht0); ho.y = f2bf(ht1); ho.z = f2bf(ht2); ho.w = f2bf(ht3);
    *reinterpret_cast<ushort4*>(&HT[(size_t)n * KP + h]) = ho;
    float4 so; so.x = sc0; so.y = sc1; so.z = sc2; so.w = sc3;
    *reinterpret_cast<float4*>(&SC[(size_t)n * KP + h]) = so;
}

// ---------------------------------------------------------------------------
// zgemm: gates GEMM + fused cell epilogue.  T3+T4 pipeline: BK=64, 10 steps
// over concat K=640 ([X|HT] splits at chunk 40), double-buffered LDS (40 KB
// -> 4 blocks/CU), counted vmcnt(5) + raw s_barrier.  Tile 64 rows x 32 j x
// 3 gates; grid 640, 256 thr (4 waves 2x2).
// ---------------------------------------------------------------------------
__global__ __launch_bounds__(256)
void zgemm(const ushort* __restrict__ X, const ushort* __restrict__ HT,
           const ushort* __restrict__ Wz, const float* __restrict__ BZ,
           const float* __restrict__ SC,
           float* __restrict__ cdst, ushort* __restrict__ Hb,
           float* __restrict__ hdst)
{
    __shared__ __attribute__((aligned(16))) ushort As[2][8][64][8];    // 16 KB
    __shared__ __attribute__((aligned(16))) ushort Bs[2][3][8][32][8]; // 24 KB

    const int b  = blockIdx.x;
    const int bj = (b % 8) * 80 + b / 8;          // bijective (640 % 8 == 0)
    const int m0 = (bj / 10) * 64, j0 = (bj % 10) * 32;

    const int t = threadIdx.x, w = t >> 6, l = t & 63;
    const int kq = l >> 4, lr = l & 15;
    const int m_off = (w >> 1) * 32, j_off = (w & 1) * 16;

    f32x4 acc[3][2] = {};

    auto STAGE = [&](int buf, int s) {
        #pragma unroll
        for (int c = 0; c < 2; ++c) {             // A: 512 slots, 2/thread
            const int slot = t + 256 * c;
            const int kb = slot >> 6, row = slot & 63;
            const int kcg = s * 8 + kb;           // global concat k-chunk
            const ushort* src = (kcg < 40)
                ? (X  + (size_t)(m0 + row) * KP + (size_t)kcg * 8)
                : (HT + (size_t)(m0 + row) * KP + (size_t)(kcg - 40) * 8);
            __builtin_amdgcn_global_load_lds((const GAS void*)src,
                (LAS void*)&As[buf][kb][row][0], 16, 0, 0);
        }
        #pragma unroll
        for (int c = 0; c < 3; ++c) {             // B: 768 slots, 3/thread
            const int slot = t + 256 * c;
            const int g = slot >> 8, rem = slot & 255;
            const int kb = rem >> 5, row = rem & 31;
            const ushort* src = Wz + ((size_t)g * KP + j0 + row) * 640
                                   + (size_t)(s * 8 + kb) * 8;
            __builtin_amdgcn_global_load_lds((const GAS void*)src,
                (LAS void*)&Bs[buf][g][kb][row][0], 16, 0, 0);
        }
    };
    auto COMPUTE = [&](int buf) {
        #pragma unroll
        for (int kk = 0; kk < 2; ++kk) {
            const int kc = kk * 4 + kq;
            bf16x8 af[2], bfr[3];
            #pragma unroll
            for (int mi = 0; mi < 2; ++mi)
                af[mi] = *reinterpret_cast<const bf16x8*>(
                    &As[buf][kc][m_off + mi * 16 + lr][0]);
            #pragma unroll
            for (int g = 0; g < 3; ++g)
                bfr[g] = *reinterpret_cast<const bf16x8*>(
                    &Bs[buf][g][kc][j_off + lr][0]);
            #pragma unroll
            for (int g = 0; g < 3; ++g)
                #pragma unroll
                for (int mi = 0; mi < 2; ++mi)
                    acc[g][mi] = __builtin_amdgcn_mfma_f32_16x16x32_bf16(
                        af[mi], bfr[g], acc[g][mi], 0, 0, 0);
        }
    };

    STAGE(0, 0);
    #pragma unroll
    for (int s = 0; s < 9; ++s) {
        STAGE((s + 1) & 1, s + 1);                // 5 loads in flight
        asm volatile("s_waitcnt vmcnt(5)" ::: "memory");
        __builtin_amdgcn_s_barrier();
        COMPUTE(s & 1);
        __builtin_amdgcn_s_barrier();             // readers done before restage
    }
    asm volatile("s_waitcnt vmcnt(0)" ::: "memory");
    __builtin_amdgcn_s_barrier();
    COMPUTE(1);                                   // step 9 -> buf 1

    // ---- fused cell epilogue (all 3 gates present per element) ----------
    const int col = l & 15, r0 = (l >> 4) * 4;
    const int gn = j0 + j_off + col;
    if (gn < 300) {
        const float bi_ = BZ[gn], bo_ = BZ[KP + gn], bu_ = BZ[2 * KP + gn];
        #pragma unroll
        for (int mi = 0; mi < 2; ++mi) {
            #pragma unroll
            for (int r = 0; r < 4; ++r) {
                const int gm = m0 + m_off + mi * 16 + r0 + r;
                const float sc = SC[(size_t)gm * KP + gn];
                const float ig = sigmoidf_(acc[0][mi][r] + bi_);
                const float og = sigmoidf_(acc[1][mi][r] + bo_);
                const float ug = tanhf   (acc[2][mi][r] + bu_);
                const float c  = ig * ug + sc;
                const float hv = og * tanhf(c);
                cdst[(size_t)gm * HH + gn] = c;
                Hb  [(size_t)gm * KP + gn] = f2bf(hv);
                if (hdst) hdst[(size_t)gm * HH + gn] = hv;
            }
        }
    }
}

// ---------------------------------------------------------------------------
extern "C" void kernel_launch(void* const* d_in, const int* in_sizes, int n_in,
                              void* d_out, int out_size, void* d_ws, size_t ws_size,
                              hipStream_t stream)
{
    const int*   word_ids   = (const int*)  d_in[0];
    const int*   child_idx  = (const int*)  d_in[1];
    const float* child_mask = (const float*)d_in[2];
    const float* emb        = (const float*)d_in[3];
    const float* w_i  = (const float*)d_in[4];  const float* b_wi = (const float*)d_in[5];
    const float* u_i  = (const float*)d_in[6];  const float* b_ui = (const float*)d_in[7];
    const float* w_f  = (const float*)d_in[8];  const float* b_wf = (const float*)d_in[9];
    const float* u_f  = (const float*)d_in[10]; const float* b_uf = (const float*)d_in[11];
    const float* w_o  = (const float*)d_in[12]; const float* b_wo = (const float*)d_in[13];
    const float* u_o  = (const float*)d_in[14]; const float* b_uo = (const float*)d_in[15];
    const float* w_u  = (const float*)d_in[16]; const float* b_wu = (const float*)d_in[17];
    const float* u_u  = (const float*)d_in[18]; const float* b_uu = (const float*)d_in[19];

    uint8_t* ws = (uint8_t*)d_ws;
    size_t off = 0;
    auto alloc = [&](size_t bytes) {
        uint8_t* p = ws + off;
        off += (bytes + 255) & ~(size_t)255;
        return p;
    };
    ushort* WfP   = (ushort*)alloc((size_t)KP * KP * 2);
    ushort* Uf    = (ushort*)alloc((size_t)KP * KP * 2);
    ushort* Wz    = (ushort*)alloc((size_t)3 * KP * 640 * 2);
    ushort* Xall  = (ushort*)alloc((size_t)LVLS * NN * KP * 2);
    ushort* WXFall= (ushort*)alloc((size_t)LVLS * NN * KP * 2);
    ushort* FPbf  = (ushort*)alloc((size_t)NN * KP * 2);
    ushort* HTbf  = (ushort*)alloc((size_t)NN * KP * 2);
    ushort* Hbf   = (ushort*)alloc((size_t)NN * KP * 2);
    float*  SCb   = (float*) alloc((size_t)NN * KP * 4);
    float*  C0    = (float*) alloc((size_t)NN * HH * 4);
    float*  BZ    = (float*) alloc(3 * KP * 4);
    float*  Bwf   = (float*) alloc(KP * 4);
    float*  BUFb  = (float*) alloc(KP * 4);

    pack_and_stage<<<18567, 256, 0, stream>>>(
        w_i, b_wi, u_i, b_ui, w_f, b_wf, u_f, b_uf,
        w_o, b_wo, u_o, b_uo, w_u, b_wu, u_u, b_uu,
        WfP, Uf, Wz, BZ, Bwf, BUFb,
        word_ids, emb, Xall);
    wxf_all_kernel<<<1920, 256, 0, stream>>>(Xall, WfP, Bwf, WXFall);

    float* h_final = (float*)d_out;
    float* c_final = (float*)d_out + (size_t)NN * HH;

    for (int lev = 0; lev < LVLS; ++lev) {
        const int*    cidx  = child_idx  + (size_t)lev * NN * KK;
        const float*  cmask = child_mask + (size_t)lev * NN * KK;
        const ushort* Xlev  = Xall   + (size_t)lev * NN * KP;
        const ushort* WXFlev= WXFall + (size_t)lev * NN * KP;
        const bool last = (lev == LVLS - 1);
        float* cdst = last ? c_final : C0;
        float* hdst = last ? h_final : nullptr;

        if (lev > 0)
            fp_kernel<<<640, 128, 0, stream>>>(Hbf, Uf, BUFb, FPbf);
        reduce_kernel<<<1024, dim3(80, 4), 0, stream>>>(
            Hbf, C0, FPbf, WXFlev, cidx, cmask, HTbf, SCb);
        zgemm<<<640, 256, 0, stream>>>(
            Xlev, HTbf, Wz, BZ, SCb, cdst, Hbf, hdst);
    }
}

// Round 7
// 513.150 us; speedup vs baseline: 1.2830x; 1.2721x over previous
//
#include <hip/hip_runtime.h>
#include <cmath>
#include <cstdint>

// ---------------------------------------------------------------------------
// DependencyTreeLSTM (R7).  Lesson history:
//  R1 persistent+grid-barrier: L2 invalidates on 8 XCDs -> 2.8x regression.
//  R2 fused level kernel: grid capped at 256 blocks -> latency-bound.
//  R3-R6: zgemm/wxf stuck at ~35-45us across register-direct, DMA BK=32/64/
//     128/160, dbuf+counted-vmcnt.  Invariant cost across ALL schedules ->
//     shared defect: staging lanes map to consecutive ROWS but global arrays
//     are row-major (640B stride) -> every global_load_lds touches 64 cache
//     lines (16B used per 64B line), 64 serialized line requests per wave.
//  R7: pre-transpose staged operands to k-chunk-major in GLOBAL memory
//     (Xall'/WfP'/Wz'/HT' = [kb][rows][8]) so staging reads base+lane*16,
//     contiguous 1KB per wave-instr (pre-swizzled-global pattern).  MFMA
//     phases / pipeline / epilogues unchanged.  reduce writes HT' k-major
//     and zeroes its k-pad chunks.
// ---------------------------------------------------------------------------

#define NN    4096
#define HH    300
#define KK    8
#define LVLS  12
#define KP    320
#define MTOT  49152   // 12*4096 rows in Xall

typedef __bf16  bf16x8 __attribute__((ext_vector_type(8)));
typedef float   f32x4  __attribute__((ext_vector_type(4)));

#define GAS __attribute__((address_space(1)))
#define LAS __attribute__((address_space(3)))

__device__ __forceinline__ float sigmoidf_(float x) {
    return 1.0f / (1.0f + expf(-x));
}
__device__ __forceinline__ ushort f2bf(float f) {   // f32 -> bf16, RNE
    union { float f; uint32_t u; } v; v.f = f;
    return (ushort)((v.u + 0x7fffu + ((v.u >> 16) & 1u)) >> 16);
}
__device__ __forceinline__ float bf2f(ushort u) {
    union { uint32_t u; float f; } v; v.u = ((uint32_t)u) << 16;
    return v.f;
}

// ---------------------------------------------------------------------------
// pack (blocks [0,3207)) + stage X' (blocks [3207, 10887)).
// Layouts:
//   WfP' [40][320][8]      (k-chunk-major)   elem (r,k) -> ((k/8)*320+r)*8+k%8
//   Uf   [320][320]        (row-major, fp_kernel register-direct)
//   Wz'  [3][80][320][8]   (k-chunk-major)
//   Xall'[40][49152][8]    (k-chunk-major)
//   BZ[3][320], Bwf[320], BUF[320]
// ---------------------------------------------------------------------------
__global__ __launch_bounds__(256)
void pack_and_stage(
    const float* __restrict__ wi, const float* __restrict__ bwi,
    const float* __restrict__ ui, const float* __restrict__ bui,
    const float* __restrict__ wf, const float* __restrict__ bwf,
    const float* __restrict__ uf, const float* __restrict__ buf_,
    const float* __restrict__ wo, const float* __restrict__ bwo,
    const float* __restrict__ uo, const float* __restrict__ buo,
    const float* __restrict__ wu, const float* __restrict__ bwu,
    const float* __restrict__ uu, const float* __restrict__ buu,
    ushort* __restrict__ WfP, ushort* __restrict__ Uf, ushort* __restrict__ Wz,
    float* __restrict__ BZ, float* __restrict__ Bwf, float* __restrict__ BUF,
    const int* __restrict__ word_ids, const float* __restrict__ emb,
    ushort* __restrict__ X)
{
    const int b = blockIdx.x;
    if (b >= 3207) {                                     // ---- stage X' ----
        int idx = (b - 3207) * 256 + threadIdx.x;        // 40 * 49152
        int kb = idx / MTOT, row = idx % MTOT;           // consecutive t -> row
        const int k0 = kb * 8;
        ushort o[8];
        if (kb < 37) {
            const float4* p = reinterpret_cast<const float4*>(
                emb + (size_t)word_ids[row] * 300 + k0);
            float4 v0 = p[0], v1 = p[1];
            o[0] = f2bf(v0.x); o[1] = f2bf(v0.y); o[2] = f2bf(v0.z); o[3] = f2bf(v0.w);
            o[4] = f2bf(v1.x); o[5] = f2bf(v1.y); o[6] = f2bf(v1.z); o[7] = f2bf(v1.w);
        } else if (kb == 37) {
            const float4 v0 = *reinterpret_cast<const float4*>(
                emb + (size_t)word_ids[row] * 300 + k0);
            o[0] = f2bf(v0.x); o[1] = f2bf(v0.y); o[2] = f2bf(v0.z); o[3] = f2bf(v0.w);
            o[4] = o[5] = o[6] = o[7] = 0;
        } else {
            o[0] = o[1] = o[2] = o[3] = o[4] = o[5] = o[6] = o[7] = 0;
        }
        ushort* dst = X + ((size_t)kb * MTOT + row) * 8;
        ushort4 a; a.x = o[0]; a.y = o[1]; a.z = o[2]; a.w = o[3];
        ushort4 c; c.x = o[4]; c.y = o[5]; c.z = o[6]; c.w = o[7];
        *reinterpret_cast<ushort4*>(dst)     = a;
        *reinterpret_cast<ushort4*>(dst + 4) = c;
        return;
    }
    int t = b * 256 + threadIdx.x;                       // ---- pack part ----
    if (t < 102400) {                                    // WfP' k-chunk-major
        int r = t / KP, k = t % KP;
        WfP[((size_t)(k >> 3) * KP + r) * 8 + (k & 7)] =
            f2bf((r < 300 && k < 300) ? wf[r * 300 + k] : 0.f);
    } else if (t < 204800) {                             // Uf row-major
        int x = t - 102400, r = x / KP, k = x % KP;
        Uf[x] = f2bf((r < 300 && k < 300) ? uf[r * 300 + k] : 0.f);
    } else if (t < 819200) {                             // Wz' [3][80][320][8]
        int x = t - 204800;
        int g = x / 204800, rem = x % 204800;
        int r = rem / 640, k = rem % 640;
        const float* W = (g == 0) ? wi : (g == 1) ? wo : wu;
        const float* U = (g == 0) ? ui : (g == 1) ? uo : uu;
        float v = 0.f;
        if (r < 300) {
            if (k < 320) { if (k < 300) v = W[r * 300 + k]; }
            else         { int kk = k - 320; if (kk < 300) v = U[r * 300 + kk]; }
        }
        Wz[(((size_t)g * 80 + (k >> 3)) * KP + r) * 8 + (k & 7)] = f2bf(v);
    } else if (t < 820160) {                             // BZ [3][320]
        int x = t - 819200, g = x / KP, r = x % KP;
        const float* bw = (g == 0) ? bwi : (g == 1) ? bwo : bwu;
        const float* bu = (g == 0) ? bui : (g == 1) ? buo : buu;
        BZ[x] = (r < 300) ? bw[r] + bu[r] : 0.f;
    } else if (t < 820480) {                             // Bwf
        int r = t - 820160;
        Bwf[r] = (r < 300) ? bwf[r] : 0.f;
    } else if (t < 820800) {                             // BUF
        int r = t - 820480;
        BUF[r] = (r < 300) ? buf_[r] : 0.f;
    }
}

// ---------------------------------------------------------------------------
// WXF_all = X_all @ w_f^T + b_wf -> bf16 [49152][320] (row-major out).
// Grid 1920, 256 thr.  BK=64 dbuf pipeline, counted vmcnt(6).
// Staging now COALESCED: X'/WfP' are k-chunk-major, lane i reads base+i*16.
// ---------------------------------------------------------------------------
__global__ __launch_bounds__(256)
void wxf_all_kernel(const ushort* __restrict__ Xp, const ushort* __restrict__ WfPp,
                    const float* __restrict__ Bwf, ushort* __restrict__ WXFall)
{
    __shared__ __attribute__((aligned(16))) ushort As[2][8][128][8];  // 32 KB
    __shared__ __attribute__((aligned(16))) ushort Bs[2][8][64][8];   // 16 KB

    const int b  = blockIdx.x;
    const int bj = (b % 8) * 240 + b / 8;         // bijective (1920 % 8 == 0)
    const int m0 = (bj / 5) * 128, n0 = (bj % 5) * 64;

    const int t = threadIdx.x, l = t & 63, w = t >> 6;
    const int m_off = (w >> 1) * 64, n_off = (w & 1) * 32;
    const int kq = l >> 4, lr = l & 15;

    f32x4 acc[4][2] = {};

    auto STAGE = [&](int buf, int s) {
        #pragma unroll
        for (int c = 0; c < 4; ++c) {             // A: 1024 slots, 4/thread
            const int slot = t + 256 * c;
            const int kb = slot >> 7, row = slot & 127;
            const ushort* src = Xp + ((size_t)(s * 8 + kb) * MTOT + m0 + row) * 8;
            __builtin_amdgcn_global_load_lds((const GAS void*)src,
                (LAS void*)&As[buf][kb][row][0], 16, 0, 0);
        }
        #pragma unroll
        for (int c = 0; c < 2; ++c) {             // B: 512 slots, 2/thread
            const int slot = t + 256 * c;
            const int kb = slot >> 6, row = slot & 63;
            const ushort* src = WfPp + ((size_t)(s * 8 + kb) * KP + n0 + row) * 8;
            __builtin_amdgcn_global_load_lds((const GAS void*)src,
                (LAS void*)&Bs[buf][kb][row][0], 16, 0, 0);
        }
    };
    auto COMPUTE = [&](int buf) {
        #pragma unroll
        for (int kk = 0; kk < 2; ++kk) {
            const int kc = kk * 4 + kq;
            bf16x8 af[4], bfr[2];
            #pragma unroll
            for (int mi = 0; mi < 4; ++mi)
                af[mi] = *reinterpret_cast<const bf16x8*>(
                    &As[buf][kc][m_off + mi * 16 + lr][0]);
            #pragma unroll
            for (int ni = 0; ni < 2; ++ni)
                bfr[ni] = *reinterpret_cast<const bf16x8*>(
                    &Bs[buf][kc][n_off + ni * 16 + lr][0]);
            #pragma unroll
            for (int mi = 0; mi < 4; ++mi)
                #pragma unroll
                for (int ni = 0; ni < 2; ++ni)
                    acc[mi][ni] = __builtin_amdgcn_mfma_f32_16x16x32_bf16(
                        af[mi], bfr[ni], acc[mi][ni], 0, 0, 0);
        }
    };

    STAGE(0, 0);
    #pragma unroll
    for (int s = 0; s < 4; ++s) {
        STAGE((s + 1) & 1, s + 1);                // 6 loads in flight
        asm volatile("s_waitcnt vmcnt(6)" ::: "memory");
        __builtin_amdgcn_s_barrier();
        COMPUTE(s & 1);
        __builtin_amdgcn_s_barrier();             // readers done before restage
    }
    asm volatile("s_waitcnt vmcnt(0)" ::: "memory");
    __builtin_amdgcn_s_barrier();
    COMPUTE(0);                                   // step 4 -> buf 0

    const int col = l & 15, r0 = (l >> 4) * 4;
    #pragma unroll
    for (int mi = 0; mi < 4; ++mi) {
        #pragma unroll
        for (int ni = 0; ni < 2; ++ni) {
            const int gn = n0 + n_off + ni * 16 + col;
            const float bb = Bwf[gn];
            #pragma unroll
            for (int r = 0; r < 4; ++r) {
                const int gm = m0 + m_off + mi * 16 + r0 + r;
                WXFall[(size_t)gm * KP + gn] = f2bf(acc[mi][ni][r] + bb);
            }
        }
    }
}

__device__ __forceinline__ int swz640(int b) { return (b % 8) * 80 + b / 8; }

// ---------------------------------------------------------------------------
// FP = Hbf @ u_f^T + b_uf  (bf16 out, [4096][320]).  Grid 640 x 128 thr.
// Register-direct (small: ~0.8 GFLOP).  Hbf/Uf row-major.
// ---------------------------------------------------------------------------
__global__ __launch_bounds__(128)
void fp_kernel(const ushort* __restrict__ Hbf, const ushort* __restrict__ Uf,
               const float* __restrict__ BUF, ushort* __restrict__ FP)
{
    const int bj = swz640((int)blockIdx.x);
    const int m0 = (bj / 10) * 64, n0 = (bj % 10) * 32;
    const int t = threadIdx.x, w = t >> 6, l = t & 63;
    const int kq = l >> 4, lr = l & 15, m_off = w * 32;

    f32x4 acc[2][2] = {};
    #pragma unroll
    for (int s = 0; s < 10; ++s) {
        const int kc = s * 4 + kq;
        bf16x8 af[2], bfr[2];
        #pragma unroll
        for (int mi = 0; mi < 2; ++mi)
            af[mi] = *reinterpret_cast<const bf16x8*>(
                Hbf + (size_t)(m0 + m_off + mi * 16 + lr) * KP + (size_t)kc * 8);
        #pragma unroll
        for (int ni = 0; ni < 2; ++ni)
            bfr[ni] = *reinterpret_cast<const bf16x8*>(
                Uf + (size_t)(n0 + ni * 16 + lr) * KP + (size_t)kc * 8);
        #pragma unroll
        for (int mi = 0; mi < 2; ++mi)
            #pragma unroll
            for (int ni = 0; ni < 2; ++ni)
                acc[mi][ni] = __builtin_amdgcn_mfma_f32_16x16x32_bf16(
                    af[mi], bfr[ni], acc[mi][ni], 0, 0, 0);
    }

    const int col = l & 15, r0 = (l >> 4) * 4;
    #pragma unroll
    for (int mi = 0; mi < 2; ++mi) {
        #pragma unroll
        for (int ni = 0; ni < 2; ++ni) {
            const int gn = n0 + ni * 16 + col;
            const float bb = BUF[gn];
            #pragma unroll
            for (int r = 0; r < 4; ++r) {
                const int gm = m0 + m_off + mi * 16 + r0 + r;
                FP[(size_t)gm * KP + gn] = f2bf(acc[mi][ni][r] + bb);
            }
        }
    }
}

// ---------------------------------------------------------------------------
// Child gather + masked sums.  4 nodes/block, branchless prefetched loads.
// HT is written K-CHUNK-MAJOR ([40][4096][8]) for zgemm's coalesced staging;
// k-pad chunks (37-upper, 38, 39) are explicitly zeroed.
// ---------------------------------------------------------------------------
__global__ __launch_bounds__(320)
void reduce_kernel(const ushort* __restrict__ Hbf, const float* __restrict__ Cst,
                   const ushort* __restrict__ FP, const ushort* __restrict__ WXF,
                   const int* __restrict__ cidx, const float* __restrict__ cmask,
                   ushort* __restrict__ HTp, float* __restrict__ SC)
{
    const int x = threadIdx.x;          // 0..79
    const int ty = threadIdx.y;         // 0..3
    const int n = blockIdx.x * 4 + ty;
    __shared__ int   ch[4][KK];
    __shared__ float mk[4][KK];
    if (x < KK) {
        ch[ty][x] = cidx[n * KK + x];
        mk[ty][x] = cmask[n * KK + x];
    }
    __syncthreads();
    if (x >= 75) {                      // zero HT' k-pad chunks
        ushort4 z; z.x = z.y = z.z = z.w = 0;
        const int pi = x - 75;          // 0..4 -> (37,4),(38,0),(38,4),(39,0),(39,4)
        const int kb = 37 + ((pi + 1) >> 1);
        const int off = ((pi & 1) ^ 1) * 4;   // pi:0->4, 1->0, 2->4, 3->0, 4->4
        *reinterpret_cast<ushort4*>(
            HTp + ((size_t)kb * NN + n) * 8 + off) = z;
        return;
    }
    const int h = x * 4;

    ushort4 hu[KK]; ushort4 fu[KK]; float4 cv[KK];
    #pragma unroll
    for (int k = 0; k < KK; ++k) {
        const size_t cr = (size_t)ch[ty][k];
        hu[k] = *reinterpret_cast<const ushort4*>(&Hbf[cr * KP + h]);
        fu[k] = *reinterpret_cast<const ushort4*>(&FP [cr * KP + h]);
        cv[k] = *reinterpret_cast<const float4*>(&Cst[cr * HH + h]);
    }

    ushort4 wxu = *reinterpret_cast<const ushort4*>(&WXF[(size_t)n * KP + h]);
    const float wx0 = bf2f(wxu.x), wx1 = bf2f(wxu.y),
                wx2 = bf2f(wxu.z), wx3 = bf2f(wxu.w);
    float ht0 = 0.f, ht1 = 0.f, ht2 = 0.f, ht3 = 0.f;
    float sc0 = 0.f, sc1 = 0.f, sc2 = 0.f, sc3 = 0.f;

    #pragma unroll
    for (int k = 0; k < KK; ++k) {
        const float m = mk[ty][k];
        if (m != 0.f) {
            ht0 += m * bf2f(hu[k].x); ht1 += m * bf2f(hu[k].y);
            ht2 += m * bf2f(hu[k].z); ht3 += m * bf2f(hu[k].w);
            sc0 += m * sigmoidf_(wx0 + bf2f(fu[k].x)) * cv[k].x;
            sc1 += m * sigmoidf_(wx1 + bf2f(fu[k].y)) * cv[k].y;
            sc2 += m * sigmoidf_(wx2 + bf2f(fu[k].z)) * cv[k].z;
            sc3 += m * sigmoidf_(wx3 + bf2f(fu[k].w)) * cv[k].w;
        }
    }
    ushort4 ho; ho.x = f2bf(ht0); ho.y = f2bf(ht1); ho.z = f2bf(ht2); ho.w = f2bf(ht3);
    *reinterpret_cast<ushort4*>(
        HTp + ((size_t)(x >> 1) * NN + n) * 8 + (x & 1) * 4) = ho;
    float4 so; so.x = sc0; so.y = sc1; so.z = sc2; so.w = sc3;
    *reinterpret_cast<float4*>(&SC[(size_t)n * KP + h]) = so;
}

// ---------------------------------------------------------------------------
// zgemm: gates GEMM + fused cell epilogue.  BK=64 dbuf pipeline, counted
// vmcnt(5).  A = [X' | HT'] (both k-chunk-major, coalesced staging; concat
// splits at global k-chunk 40).  B = Wz' k-chunk-major.  Tile 64r x 32j x
// 3 gates; grid 640, 256 thr.
// ---------------------------------------------------------------------------
__global__ __launch_bounds__(256)
void zgemm(const ushort* __restrict__ Xlev, const ushort* __restrict__ HTp,
           const ushort* __restrict__ Wzp, const float* __restrict__ BZ,
           const float* __restrict__ SC,
           float* __restrict__ cdst, ushort* __restrict__ Hb,
           float* __restrict__ hdst)
{
    __shared__ __attribute__((aligned(16))) ushort As[2][8][64][8];    // 16 KB
    __shared__ __attribute__((aligned(16))) ushort Bs[2][3][8][32][8]; // 24 KB

    const int b  = blockIdx.x;
    const int bj = (b % 8) * 80 + b / 8;          // bijective (640 % 8 == 0)
    const int m0 = (bj / 10) * 64, j0 = (bj % 10) * 32;

    const int t = threadIdx.x, w = t >> 6, l = t & 63;
    const int kq = l >> 4, lr = l & 15;
    const int m_off = (w >> 1) * 32, j_off = (w & 1) * 16;

    f32x4 acc[3][2] = {};

    auto STAGE = [&](int buf, int s) {
        #pragma unroll
        for (int c = 0; c < 2; ++c) {             // A: 512 slots, 2/thread
            const int slot = t + 256 * c;
            const int kb = slot >> 6, row = slot & 63;
            const int kcg = s * 8 + kb;           // global concat k-chunk
            const ushort* src = (kcg < 40)
                ? (Xlev + ((size_t)kcg * MTOT + m0 + row) * 8)
                : (HTp  + ((size_t)(kcg - 40) * NN + m0 + row) * 8);
            __builtin_amdgcn_global_load_lds((const GAS void*)src,
                (LAS void*)&As[buf][kb][row][0], 16, 0, 0);
        }
        #pragma unroll
        for (int c = 0; c < 3; ++c) {             // B: 768 slots, 3/thread
            const int slot = t + 256 * c;
            const int g = slot >> 8, rem = slot & 255;
            const int kb = rem >> 5, row = rem & 31;
            const ushort* src = Wzp +
                (((size_t)g * 80 + s * 8 + kb) * KP + j0 + row) * 8;
            __builtin_amdgcn_global_load_lds((const GAS void*)src,
                (LAS void*)&Bs[buf][g][kb][row][0], 16, 0, 0);
        }
    };
    auto COMPUTE = [&](int buf) {
        #pragma unroll
        for (int kk = 0; kk < 2; ++kk) {
            const int kc = kk * 4 + kq;
            bf16x8 af[2], bfr[3];
            #pragma unroll
            for (int mi = 0; mi < 2; ++mi)
                af[mi] = *reinterpret_cast<const bf16x8*>(
                    &As[buf][kc][m_off + mi * 16 + lr][0]);
            #pragma unroll
            for (int g = 0; g < 3; ++g)
                bfr[g] = *reinterpret_cast<const bf16x8*>(
                    &Bs[buf][g][kc][j_off + lr][0]);
            #pragma unroll
            for (int g = 0; g < 3; ++g)
                #pragma unroll
                for (int mi = 0; mi < 2; ++mi)
                    acc[g][mi] = __builtin_amdgcn_mfma_f32_16x16x32_bf16(
                        af[mi], bfr[g], acc[g][mi], 0, 0, 0);
        }
    };

    STAGE(0, 0);
    #pragma unroll
    for (int s = 0; s < 9; ++s) {
        STAGE((s + 1) & 1, s + 1);                // 5 loads in flight
        asm volatile("s_waitcnt vmcnt(5)" ::: "memory");
        __builtin_amdgcn_s_barrier();
        COMPUTE(s & 1);
        __builtin_amdgcn_s_barrier();             // readers done before restage
    }
    asm volatile("s_waitcnt vmcnt(0)" ::: "memory");
    __builtin_amdgcn_s_barrier();
    COMPUTE(1);                                   // step 9 -> buf 1

    // ---- fused cell epilogue (all 3 gates present per element) ----------
    const int col = l & 15, r0 = (l >> 4) * 4;
    const int gn = j0 + j_off + col;
    if (gn < 300) {
        const float bi_ = BZ[gn], bo_ = BZ[KP + gn], bu_ = BZ[2 * KP + gn];
        #pragma unroll
        for (int mi = 0; mi < 2; ++mi) {
            #pragma unroll
            for (int r = 0; r < 4; ++r) {
                const int gm = m0 + m_off + mi * 16 + r0 + r;
                const float sc = SC[(size_t)gm * KP + gn];
                const float ig = sigmoidf_(acc[0][mi][r] + bi_);
                const float og = sigmoidf_(acc[1][mi][r] + bo_);
                const float ug = tanhf   (acc[2][mi][r] + bu_);
                const float c  = ig * ug + sc;
                const float hv = og * tanhf(c);
                cdst[(size_t)gm * HH + gn] = c;
                Hb  [(size_t)gm * KP + gn] = f2bf(hv);
                if (hdst) hdst[(size_t)gm * HH + gn] = hv;
            }
        }
    }
}

// ---------------------------------------------------------------------------
extern "C" void kernel_launch(void* const* d_in, const int* in_sizes, int n_in,
                              void* d_out, int out_size, void* d_ws, size_t ws_size,
                              hipStream_t stream)
{
    const int*   word_ids   = (const int*)  d_in[0];
    const int*   child_idx  = (const int*)  d_in[1];
    const float* child_mask = (const float*)d_in[2];
    const float* emb        = (const float*)d_in[3];
    const float* w_i  = (const float*)d_in[4];  const float* b_wi = (const float*)d_in[5];
    const float* u_i  = (const float*)d_in[6];  const float* b_ui = (const float*)d_in[7];
    const float* w_f  = (const float*)d_in[8];  const float* b_wf = (const float*)d_in[9];
    const float* u_f  = (const float*)d_in[10]; const float* b_uf = (const float*)d_in[11];
    const float* w_o  = (const float*)d_in[12]; const float* b_wo = (const float*)d_in[13];
    const float* u_o  = (const float*)d_in[14]; const float* b_uo = (const float*)d_in[15];
    const float* w_u  = (const float*)d_in[16]; const float* b_wu = (const float*)d_in[17];
    const float* u_u  = (const float*)d_in[18]; const float* b_uu = (const float*)d_in[19];

    uint8_t* ws = (uint8_t*)d_ws;
    size_t off = 0;
    auto alloc = [&](size_t bytes) {
        uint8_t* p = ws + off;
        off += (bytes + 255) & ~(size_t)255;
        return p;
    };
    ushort* WfP   = (ushort*)alloc((size_t)KP * KP * 2);          // k-major
    ushort* Uf    = (ushort*)alloc((size_t)KP * KP * 2);          // row-major
    ushort* Wz    = (ushort*)alloc((size_t)3 * KP * 640 * 2);     // k-major
    ushort* Xall  = (ushort*)alloc((size_t)40 * MTOT * 8 * 2);    // k-major
    ushort* WXFall= (ushort*)alloc((size_t)LVLS * NN * KP * 2);   // row-major
    ushort* FPbf  = (ushort*)alloc((size_t)NN * KP * 2);          // row-major
    ushort* HTbf  = (ushort*)alloc((size_t)40 * NN * 8 * 2);      // k-major
    ushort* Hbf   = (ushort*)alloc((size_t)NN * KP * 2);          // row-major
    float*  SCb   = (float*) alloc((size_t)NN * KP * 4);
    float*  C0    = (float*) alloc((size_t)NN * HH * 4);
    float*  BZ    = (float*) alloc(3 * KP * 4);
    float*  Bwf   = (float*) alloc(KP * 4);
    float*  BUFb  = (float*) alloc(KP * 4);

    pack_and_stage<<<10887, 256, 0, stream>>>(
        w_i, b_wi, u_i, b_ui, w_f, b_wf, u_f, b_uf,
        w_o, b_wo, u_o, b_uo, w_u, b_wu, u_u, b_uu,
        WfP, Uf, Wz, BZ, Bwf, BUFb,
        word_ids, emb, Xall);
    wxf_all_kernel<<<1920, 256, 0, stream>>>(Xall, WfP, Bwf, WXFall);

    float* h_final = (float*)d_out;
    float* c_final = (float*)d_out + (size_t)NN * HH;

    for (int lev = 0; lev < LVLS; ++lev) {
        const int*    cidx  = child_idx  + (size_t)lev * NN * KK;
        const float*  cmask = child_mask + (size_t)lev * NN * KK;
        const ushort* Xlev  = Xall + (size_t)lev * NN * 8;        // k-major view
        const ushort* WXFlev= WXFall + (size_t)lev * NN * KP;
        const bool last = (lev == LVLS - 1);
        float* cdst = last ? c_final : C0;
        float* hdst = last ? h_final : nullptr;

        if (lev > 0)
            fp_kernel<<<640, 128, 0, stream>>>(Hbf, Uf, BUFb, FPbf);
        reduce_kernel<<<1024, dim3(80, 4), 0, stream>>>(
            Hbf, C0, FPbf, WXFlev, cidx, cmask, HTbf, SCb);
        zgemm<<<640, 256, 0, stream>>>(
            Xlev, HTbf, Wz, BZ, SCb, cdst, Hbf, hdst);
    }
}

// Round 8
// 481.672 us; speedup vs baseline: 1.3669x; 1.0654x over previous
//
#include <hip/hip_runtime.h>
#include <cmath>
#include <cstdint>

// ---------------------------------------------------------------------------
// DependencyTreeLSTM (R8).  Lesson history:
//  R1 persistent grid-barrier: XCD L2 invalidates -> 2.8x regression.
//  R2 fused level kernel: 256-block grid cap -> latency-bound.
//  R3-R6: GEMMs invariant ~40us across schedules -> shared defect was
//     UNCOALESCED STAGING (lane->row at 640B stride = 64 lines/wave-load).
//  R7: k-chunk-major global layouts -> coalesced global_load_lds: 652->513.
//  R8: apply the proven pattern twice more:
//   (a) hoist X-half of gates GEMM to prologue: ZW = X_all @ [wf|wi|wo|wu]^T
//       (one big coalesced dbuf GEMM, wxf structure, N=1280).  Per-level
//       zgemm K: 640 -> 320 (HT half only), X-half added in epilogue (bf16
//       addend -- precedented by the f-gate WXF+FP path).
//   (b) fp -> coalesced staged dbuf GEMM (A = H' k-major written by zgemm,
//       B = Uf' k-major), replacing R3-style register-direct loads.
// ---------------------------------------------------------------------------

#define NN    4096
#define HH    300
#define KK    8
#define LVLS  12
#define KP    320
#define MTOT  49152   // 12*4096 rows in Xall
#define NW    1280    // ZW columns: [wf|wi|wo|wu]

typedef __bf16  bf16x8 __attribute__((ext_vector_type(8)));
typedef float   f32x4  __attribute__((ext_vector_type(4)));

#define GAS __attribute__((address_space(1)))
#define LAS __attribute__((address_space(3)))

__device__ __forceinline__ float sigmoidf_(float x) {
    return 1.0f / (1.0f + expf(-x));
}
__device__ __forceinline__ ushort f2bf(float f) {   // f32 -> bf16, RNE
    union { float f; uint32_t u; } v; v.f = f;
    return (ushort)((v.u + 0x7fffu + ((v.u >> 16) & 1u)) >> 16);
}
__device__ __forceinline__ float bf2f(ushort u) {
    union { uint32_t u; float f; } v; v.u = ((uint32_t)u) << 16;
    return v.f;
}

// ---------------------------------------------------------------------------
// pack (blocks [0,3527)) + stage X' (blocks [3527, 11207)).
// Layouts (all k-chunk-major = [k/8][cols][8], coalesced staging):
//   W4  [40][1280][8]   rows: 0-319 wf, 320-639 wi, 640-959 wo, 960-1279 wu
//   Uf' [40][320][8]
//   WzU [3][40][320][8] u_i / u_o / u_u
//   Xall'[40][49152][8]
//   BZ[3][320]=b_w+b_u (i,o,u), Bwf[320], BUF[320]
//   H'  [40][4096][8]: zero the k-pad elems (k>=300) once here.
// ---------------------------------------------------------------------------
__global__ __launch_bounds__(256)
void pack_and_stage(
    const float* __restrict__ wi, const float* __restrict__ bwi,
    const float* __restrict__ ui, const float* __restrict__ bui,
    const float* __restrict__ wf, const float* __restrict__ bwf,
    const float* __restrict__ uf, const float* __restrict__ buf_,
    const float* __restrict__ wo, const float* __restrict__ bwo,
    const float* __restrict__ uo, const float* __restrict__ buo,
    const float* __restrict__ wu, const float* __restrict__ bwu,
    const float* __restrict__ uu, const float* __restrict__ buu,
    ushort* __restrict__ W4, ushort* __restrict__ Ufp, ushort* __restrict__ WzU,
    float* __restrict__ BZ, float* __restrict__ Bwf, float* __restrict__ BUF,
    ushort* __restrict__ Hk,
    const int* __restrict__ word_ids, const float* __restrict__ emb,
    ushort* __restrict__ X)
{
    const int b = blockIdx.x;
    if (b >= 3527) {                                     // ---- stage X' ----
        int idx = (b - 3527) * 256 + threadIdx.x;        // 40 * 49152
        int kb = idx / MTOT, row = idx % MTOT;
        const int k0 = kb * 8;
        ushort o[8];
        if (kb < 37) {
            const float4* p = reinterpret_cast<const float4*>(
                emb + (size_t)word_ids[row] * 300 + k0);
            float4 v0 = p[0], v1 = p[1];
            o[0] = f2bf(v0.x); o[1] = f2bf(v0.y); o[2] = f2bf(v0.z); o[3] = f2bf(v0.w);
            o[4] = f2bf(v1.x); o[5] = f2bf(v1.y); o[6] = f2bf(v1.z); o[7] = f2bf(v1.w);
        } else if (kb == 37) {
            const float4 v0 = *reinterpret_cast<const float4*>(
                emb + (size_t)word_ids[row] * 300 + k0);
            o[0] = f2bf(v0.x); o[1] = f2bf(v0.y); o[2] = f2bf(v0.z); o[3] = f2bf(v0.w);
            o[4] = o[5] = o[6] = o[7] = 0;
        } else {
            o[0] = o[1] = o[2] = o[3] = o[4] = o[5] = o[6] = o[7] = 0;
        }
        ushort* dst = X + ((size_t)kb * MTOT + row) * 8;
        ushort4 a; a.x = o[0]; a.y = o[1]; a.z = o[2]; a.w = o[3];
        ushort4 c; c.x = o[4]; c.y = o[5]; c.z = o[6]; c.w = o[7];
        *reinterpret_cast<ushort4*>(dst)     = a;
        *reinterpret_cast<ushort4*>(dst + 4) = c;
        return;
    }
    int t = b * 256 + threadIdx.x;                       // ---- pack part ----
    if (t < 409600) {                                    // W4 [40][1280][8]
        int gate = t / 102400, rem = t % 102400;
        int r = rem / 320, k = rem % 320;
        const float* W = (gate == 0) ? wf : (gate == 1) ? wi
                       : (gate == 2) ? wo : wu;
        float v = (r < 300 && k < 300) ? W[r * 300 + k] : 0.f;
        W4[((size_t)(k >> 3) * NW + gate * 320 + r) * 8 + (k & 7)] = f2bf(v);
    } else if (t < 512000) {                             // Uf' [40][320][8]
        int x = t - 409600, r = x / 320, k = x % 320;
        Ufp[((size_t)(k >> 3) * KP + r) * 8 + (k & 7)] =
            f2bf((r < 300 && k < 300) ? uf[r * 300 + k] : 0.f);
    } else if (t < 819200) {                             // WzU [3][40][320][8]
        int x = t - 512000;
        int g = x / 102400, rem = x % 102400;
        int r = rem / 320, k = rem % 320;
        const float* U = (g == 0) ? ui : (g == 1) ? uo : uu;
        WzU[(((size_t)g * 40 + (k >> 3)) * KP + r) * 8 + (k & 7)] =
            f2bf((r < 300 && k < 300) ? U[r * 300 + k] : 0.f);
    } else if (t < 820160) {                             // BZ [3][320]
        int x = t - 819200, g = x / KP, r = x % KP;
        const float* bw = (g == 0) ? bwi : (g == 1) ? bwo : bwu;
        const float* bu = (g == 0) ? bui : (g == 1) ? buo : buu;
        BZ[x] = (r < 300) ? bw[r] + bu[r] : 0.f;
    } else if (t < 820480) {                             // Bwf
        int r = t - 820160;
        Bwf[r] = (r < 300) ? bwf[r] : 0.f;
    } else if (t < 820800) {                             // BUF
        int r = t - 820480;
        BUF[r] = (r < 300) ? buf_[r] : 0.f;
    } else if (t < 902720) {                             // H' k-pads -> 0
        int x = t - 820800;                              // 4096 * 20
        int row = x / 20, pe = x % 20;
        int k = 300 + pe;
        Hk[((size_t)(k >> 3) * NN + row) * 8 + (k & 7)] = 0;
    }
}

// ---------------------------------------------------------------------------
// ZW = X_all @ W4^T (+b_wf on cols<320) -> bf16 [49152][1280].
// Grid 7680 (384 m x 20 n), 256 thr, 128x64 tile, BK=64 dbuf, vmcnt(6).
// Cols 0-319 = WXF (read by reduce); 320+g*320 = X-half of gate g (zgemm).
// ---------------------------------------------------------------------------
__global__ __launch_bounds__(256)
void zx_all_kernel(const ushort* __restrict__ Xp, const ushort* __restrict__ W4,
                   const float* __restrict__ Bwf, ushort* __restrict__ ZW)
{
    __shared__ __attribute__((aligned(16))) ushort As[2][8][128][8];  // 32 KB
    __shared__ __attribute__((aligned(16))) ushort Bs[2][8][64][8];   // 16 KB

    const int b  = blockIdx.x;
    const int bj = (b % 8) * 960 + b / 8;         // bijective (7680 % 8 == 0)
    const int m0 = (bj / 20) * 128, n0 = (bj % 20) * 64;

    const int t = threadIdx.x, l = t & 63, w = t >> 6;
    const int m_off = (w >> 1) * 64, n_off = (w & 1) * 32;
    const int kq = l >> 4, lr = l & 15;

    f32x4 acc[4][2] = {};

    auto STAGE = [&](int buf, int s) {
        #pragma unroll
        for (int c = 0; c < 4; ++c) {             // A: 1024 slots, 4/thread
            const int slot = t + 256 * c;
            const int kb = slot >> 7, row = slot & 127;
            const ushort* src = Xp + ((size_t)(s * 8 + kb) * MTOT + m0 + row) * 8;
            __builtin_amdgcn_global_load_lds((const GAS void*)src,
                (LAS void*)&As[buf][kb][row][0], 16, 0, 0);
        }
        #pragma unroll
        for (int c = 0; c < 2; ++c) {             // B: 512 slots, 2/thread
            const int slot = t + 256 * c;
            const int kb = slot >> 6, row = slot & 63;
            const ushort* src = W4 + ((size_t)(s * 8 + kb) * NW + n0 + row) * 8;
            __builtin_amdgcn_global_load_lds((const GAS void*)src,
                (LAS void*)&Bs[buf][kb][row][0], 16, 0, 0);
        }
    };
    auto COMPUTE = [&](int buf) {
        #pragma unroll
        for (int kk = 0; kk < 2; ++kk) {
            const int kc = kk * 4 + kq;
            bf16x8 af[4], bfr[2];
            #pragma unroll
            for (int mi = 0; mi < 4; ++mi)
                af[mi] = *reinterpret_cast<const bf16x8*>(
                    &As[buf][kc][m_off + mi * 16 + lr][0]);
            #pragma unroll
            for (int ni = 0; ni < 2; ++ni)
                bfr[ni] = *reinterpret_cast<const bf16x8*>(
                    &Bs[buf][kc][n_off + ni * 16 + lr][0]);
            #pragma unroll
            for (int mi = 0; mi < 4; ++mi)
                #pragma unroll
                for (int ni = 0; ni < 2; ++ni)
                    acc[mi][ni] = __builtin_amdgcn_mfma_f32_16x16x32_bf16(
                        af[mi], bfr[ni], acc[mi][ni], 0, 0, 0);
        }
    };

    STAGE(0, 0);
    #pragma unroll
    for (int s = 0; s < 4; ++s) {
        STAGE((s + 1) & 1, s + 1);                // 6 loads in flight
        asm volatile("s_waitcnt vmcnt(6)" ::: "memory");
        __builtin_amdgcn_s_barrier();
        COMPUTE(s & 1);
        __builtin_amdgcn_s_barrier();
    }
    asm volatile("s_waitcnt vmcnt(0)" ::: "memory");
    __builtin_amdgcn_s_barrier();
    COMPUTE(0);                                   // step 4 -> buf 0

    const int col = l & 15, r0 = (l >> 4) * 4;
    #pragma unroll
    for (int mi = 0; mi < 4; ++mi) {
        #pragma unroll
        for (int ni = 0; ni < 2; ++ni) {
            const int gn = n0 + n_off + ni * 16 + col;
            const float bb = (gn < 320) ? Bwf[gn] : 0.f;
            #pragma unroll
            for (int r = 0; r < 4; ++r) {
                const int gm = m0 + m_off + mi * 16 + r0 + r;
                ZW[(size_t)gm * NW + gn] = f2bf(acc[mi][ni][r] + bb);
            }
        }
    }
}

// ---------------------------------------------------------------------------
// FP = H @ u_f^T + b_uf -> bf16 [4096][320] row-major.  Coalesced staged
// dbuf GEMM: A = H' k-major (written by zgemm), B = Uf' k-major.
// Grid 640 (64 m x 10 j), 256 thr, tile 64x32, BK=64, 5 steps, vmcnt(3).
// ---------------------------------------------------------------------------
__global__ __launch_bounds__(256)
void fp_kernel(const ushort* __restrict__ Hk, const ushort* __restrict__ Ufp,
               const float* __restrict__ BUFb, ushort* __restrict__ FP)
{
    __shared__ __attribute__((aligned(16))) ushort As[2][8][64][8];   // 16 KB
    __shared__ __attribute__((aligned(16))) ushort Bs[2][8][32][8];   //  8 KB

    const int b  = blockIdx.x;
    const int bj = (b % 8) * 80 + b / 8;          // bijective (640 % 8 == 0)
    const int m0 = (bj / 10) * 64, j0 = (bj % 10) * 32;

    const int t = threadIdx.x, w = t >> 6, l = t & 63;
    const int kq = l >> 4, lr = l & 15;
    const int m_off = (w >> 1) * 32, j_off = (w & 1) * 16;

    f32x4 acc[2] = {};

    auto STAGE = [&](int buf, int s) {
        #pragma unroll
        for (int c = 0; c < 2; ++c) {             // A: 512 slots, 2/thread
            const int slot = t + 256 * c;
            const int kb = slot >> 6, row = slot & 63;
            const ushort* src = Hk + ((size_t)(s * 8 + kb) * NN + m0 + row) * 8;
            __builtin_amdgcn_global_load_lds((const GAS void*)src,
                (LAS void*)&As[buf][kb][row][0], 16, 0, 0);
        }
        {                                         // B: 256 slots, 1/thread
            const int kb = t >> 5, row = t & 31;
            const ushort* src = Ufp + ((size_t)(s * 8 + kb) * KP + j0 + row) * 8;
            __builtin_amdgcn_global_load_lds((const GAS void*)src,
                (LAS void*)&Bs[buf][kb][row][0], 16, 0, 0);
        }
    };
    auto COMPUTE = [&](int buf) {
        #pragma unroll
        for (int kk = 0; kk < 2; ++kk) {
            const int kc = kk * 4 + kq;
            bf16x8 af[2], bf;
            #pragma unroll
            for (int mi = 0; mi < 2; ++mi)
                af[mi] = *reinterpret_cast<const bf16x8*>(
                    &As[buf][kc][m_off + mi * 16 + lr][0]);
            bf = *reinterpret_cast<const bf16x8*>(
                    &Bs[buf][kc][j_off + lr][0]);
            #pragma unroll
            for (int mi = 0; mi < 2; ++mi)
                acc[mi] = __builtin_amdgcn_mfma_f32_16x16x32_bf16(
                    af[mi], bf, acc[mi], 0, 0, 0);
        }
    };

    STAGE(0, 0);
    #pragma unroll
    for (int s = 0; s < 4; ++s) {
        STAGE((s + 1) & 1, s + 1);                // 3 loads in flight
        asm volatile("s_waitcnt vmcnt(3)" ::: "memory");
        __builtin_amdgcn_s_barrier();
        COMPUTE(s & 1);
        __builtin_amdgcn_s_barrier();
    }
    asm volatile("s_waitcnt vmcnt(0)" ::: "memory");
    __builtin_amdgcn_s_barrier();
    COMPUTE(0);                                   // step 4 -> buf 0

    const int col = l & 15, r0 = (l >> 4) * 4;
    const int gn = j0 + j_off + col;
    if (gn < 300) {
        const float bb = BUFb[gn];
        #pragma unroll
        for (int mi = 0; mi < 2; ++mi)
            #pragma unroll
            for (int r = 0; r < 4; ++r)
                FP[(size_t)(m0 + m_off + mi * 16 + r0 + r) * KP + gn] =
                    f2bf(acc[mi][r] + bb);
    }
}

// ---------------------------------------------------------------------------
// Child gather + masked sums.  4 nodes/block, branchless prefetched loads.
// WXF = ZW cols 0-319 (stride NW).  HT written k-chunk-major + pads zeroed.
// ---------------------------------------------------------------------------
__global__ __launch_bounds__(320)
void reduce_kernel(const ushort* __restrict__ Hbf, const float* __restrict__ Cst,
                   const ushort* __restrict__ FP, const ushort* __restrict__ ZWlev,
                   const int* __restrict__ cidx, const float* __restrict__ cmask,
                   ushort* __restrict__ HTp, float* __restrict__ SC)
{
    const int x = threadIdx.x;          // 0..79
    const int ty = threadIdx.y;         // 0..3
    const int n = blockIdx.x * 4 + ty;
    __shared__ int   ch[4][KK];
    __shared__ float mk[4][KK];
    if (x < KK) {
        ch[ty][x] = cidx[n * KK + x];
        mk[ty][x] = cmask[n * KK + x];
    }
    __syncthreads();
    if (x >= 75) {                      // zero HT' k-pad chunks
        ushort4 z; z.x = z.y = z.z = z.w = 0;
        const int pi = x - 75;          // (37,4),(38,0),(38,4),(39,0),(39,4)
        const int kb = 37 + ((pi + 1) >> 1);
        const int off = ((pi & 1) ^ 1) * 4;
        *reinterpret_cast<ushort4*>(
            HTp + ((size_t)kb * NN + n) * 8 + off) = z;
        return;
    }
    const int h = x * 4;

    ushort4 hu[KK]; ushort4 fu[KK]; float4 cv[KK];
    #pragma unroll
    for (int k = 0; k < KK; ++k) {
        const size_t cr = (size_t)ch[ty][k];
        hu[k] = *reinterpret_cast<const ushort4*>(&Hbf[cr * KP + h]);
        fu[k] = *reinterpret_cast<const ushort4*>(&FP [cr * KP + h]);
        cv[k] = *reinterpret_cast<const float4*>(&Cst[cr * HH + h]);
    }

    ushort4 wxu = *reinterpret_cast<const ushort4*>(&ZWlev[(size_t)n * NW + h]);
    const float wx0 = bf2f(wxu.x), wx1 = bf2f(wxu.y),
                wx2 = bf2f(wxu.z), wx3 = bf2f(wxu.w);
    float ht0 = 0.f, ht1 = 0.f, ht2 = 0.f, ht3 = 0.f;
    float sc0 = 0.f, sc1 = 0.f, sc2 = 0.f, sc3 = 0.f;

    #pragma unroll
    for (int k = 0; k < KK; ++k) {
        const float m = mk[ty][k];
        if (m != 0.f) {
            ht0 += m * bf2f(hu[k].x); ht1 += m * bf2f(hu[k].y);
            ht2 += m * bf2f(hu[k].z); ht3 += m * bf2f(hu[k].w);
            sc0 += m * sigmoidf_(wx0 + bf2f(fu[k].x)) * cv[k].x;
            sc1 += m * sigmoidf_(wx1 + bf2f(fu[k].y)) * cv[k].y;
            sc2 += m * sigmoidf_(wx2 + bf2f(fu[k].z)) * cv[k].z;
            sc3 += m * sigmoidf_(wx3 + bf2f(fu[k].w)) * cv[k].w;
        }
    }
    ushort4 ho; ho.x = f2bf(ht0); ho.y = f2bf(ht1); ho.z = f2bf(ht2); ho.w = f2bf(ht3);
    *reinterpret_cast<ushort4*>(
        HTp + ((size_t)(x >> 1) * NN + n) * 8 + (x & 1) * 4) = ho;
    float4 so; so.x = sc0; so.y = sc1; so.z = sc2; so.w = sc3;
    *reinterpret_cast<float4*>(&SC[(size_t)n * KP + h]) = so;
}

// ---------------------------------------------------------------------------
// zgemm: HT-half gates GEMM (K=320, 5 steps) + X-half addend from ZW +
// fused cell epilogue.  A = HT' k-major, B = WzU k-major.  Tile 64r x 32j x
// 3 gates; grid 640, 256 thr; dbuf, vmcnt(5).  Writes C, H row-major (for
// reduce gather) and H' k-major (for next level's fp staging).
// ---------------------------------------------------------------------------
__global__ __launch_bounds__(256)
void zgemm(const ushort* __restrict__ HTp, const ushort* __restrict__ WzU,
           const float* __restrict__ BZ, const float* __restrict__ SC,
           const ushort* __restrict__ ZXlev,
           float* __restrict__ cdst, ushort* __restrict__ Hb,
           ushort* __restrict__ Hk, float* __restrict__ hdst)
{
    __shared__ __attribute__((aligned(16))) ushort As[2][8][64][8];    // 16 KB
    __shared__ __attribute__((aligned(16))) ushort Bs[2][3][8][32][8]; // 24 KB

    const int b  = blockIdx.x;
    const int bj = (b % 8) * 80 + b / 8;          // bijective (640 % 8 == 0)
    const int m0 = (bj / 10) * 64, j0 = (bj % 10) * 32;

    const int t = threadIdx.x, w = t >> 6, l = t & 63;
    const int kq = l >> 4, lr = l & 15;
    const int m_off = (w >> 1) * 32, j_off = (w & 1) * 16;

    f32x4 acc[3][2] = {};

    auto STAGE = [&](int buf, int s) {
        #pragma unroll
        for (int c = 0; c < 2; ++c) {             // A: 512 slots, 2/thread
            const int slot = t + 256 * c;
            const int kb = slot >> 6, row = slot & 63;
            const ushort* src = HTp + ((size_t)(s * 8 + kb) * NN + m0 + row) * 8;
            __builtin_amdgcn_global_load_lds((const GAS void*)src,
                (LAS void*)&As[buf][kb][row][0], 16, 0, 0);
        }
        #pragma unroll
        for (int c = 0; c < 3; ++c) {             // B: 768 slots, 3/thread
            const int slot = t + 256 * c;
            const int g = slot >> 8, rem = slot & 255;
            const int kb = rem >> 5, row = rem & 31;
            const ushort* src = WzU +
                (((size_t)g * 40 + s * 8 + kb) * KP + j0 + row) * 8;
            __builtin_amdgcn_global_load_lds((const GAS void*)src,
                (LAS void*)&Bs[buf][g][kb][row][0], 16, 0, 0);
        }
    };
    auto COMPUTE = [&](int buf) {
        #pragma unroll
        for (int kk = 0; kk < 2; ++kk) {
            const int kc = kk * 4 + kq;
            bf16x8 af[2], bfr[3];
            #pragma unroll
            for (int mi = 0; mi < 2; ++mi)
                af[mi] = *reinterpret_cast<const bf16x8*>(
                    &As[buf][kc][m_off + mi * 16 + lr][0]);
            #pragma unroll
            for (int g = 0; g < 3; ++g)
                bfr[g] = *reinterpret_cast<const bf16x8*>(
                    &Bs[buf][g][kc][j_off + lr][0]);
            #pragma unroll
            for (int g = 0; g < 3; ++g)
                #pragma unroll
                for (int mi = 0; mi < 2; ++mi)
                    acc[g][mi] = __builtin_amdgcn_mfma_f32_16x16x32_bf16(
                        af[mi], bfr[g], acc[g][mi], 0, 0, 0);
        }
    };

    STAGE(0, 0);
    #pragma unroll
    for (int s = 0; s < 4; ++s) {
        STAGE((s + 1) & 1, s + 1);                // 5 loads in flight
        asm volatile("s_waitcnt vmcnt(5)" ::: "memory");
        __builtin_amdgcn_s_barrier();
        COMPUTE(s & 1);
        __builtin_amdgcn_s_barrier();
    }
    asm volatile("s_waitcnt vmcnt(0)" ::: "memory");
    __builtin_amdgcn_s_barrier();
    COMPUTE(0);                                   // step 4 -> buf 0

    // ---- epilogue: + X-half (ZW) + bias -> cell update ------------------
    const int col = l & 15, r0 = (l >> 4) * 4;
    const int gn = j0 + j_off + col;
    if (gn < 300) {
        const float bi_ = BZ[gn], bo_ = BZ[KP + gn], bu_ = BZ[2 * KP + gn];
        #pragma unroll
        for (int mi = 0; mi < 2; ++mi) {
            #pragma unroll
            for (int r = 0; r < 4; ++r) {
                const int gm = m0 + m_off + mi * 16 + r0 + r;
                const size_t zb = (size_t)gm * NW + 320 + gn;
                const float zi = bf2f(ZXlev[zb]);
                const float zo = bf2f(ZXlev[zb + 320]);
                const float zu = bf2f(ZXlev[zb + 640]);
                const float sc = SC[(size_t)gm * KP + gn];
                const float ig = sigmoidf_(acc[0][mi][r] + zi + bi_);
                const float og = sigmoidf_(acc[1][mi][r] + zo + bo_);
                const float ug = tanhf   (acc[2][mi][r] + zu + bu_);
                const float c  = ig * ug + sc;
                const float hv = og * tanhf(c);
                cdst[(size_t)gm * HH + gn] = c;
                const ushort hb = f2bf(hv);
                Hb[(size_t)gm * KP + gn] = hb;
                Hk[((size_t)(gn >> 3) * NN + gm) * 8 + (gn & 7)] = hb;
                if (hdst) hdst[(size_t)gm * HH + gn] = hv;
            }
        }
    }
}

// ---------------------------------------------------------------------------
extern "C" void kernel_launch(void* const* d_in, const int* in_sizes, int n_in,
                              void* d_out, int out_size, void* d_ws, size_t ws_size,
                              hipStream_t stream)
{
    const int*   word_ids   = (const int*)  d_in[0];
    const int*   child_idx  = (const int*)  d_in[1];
    const float* child_mask = (const float*)d_in[2];
    const float* emb        = (const float*)d_in[3];
    const float* w_i  = (const float*)d_in[4];  const float* b_wi = (const float*)d_in[5];
    const float* u_i  = (const float*)d_in[6];  const float* b_ui = (const float*)d_in[7];
    const float* w_f  = (const float*)d_in[8];  const float* b_wf = (const float*)d_in[9];
    const float* u_f  = (const float*)d_in[10]; const float* b_uf = (const float*)d_in[11];
    const float* w_o  = (const float*)d_in[12]; const float* b_wo = (const float*)d_in[13];
    const float* u_o  = (const float*)d_in[14]; const float* b_uo = (const float*)d_in[15];
    const float* w_u  = (const float*)d_in[16]; const float* b_wu = (const float*)d_in[17];
    const float* u_u  = (const float*)d_in[18]; const float* b_uu = (const float*)d_in[19];

    uint8_t* ws = (uint8_t*)d_ws;
    size_t off = 0;
    auto alloc = [&](size_t bytes) {
        uint8_t* p = ws + off;
        off += (bytes + 255) & ~(size_t)255;
        return p;
    };
    ushort* W4    = (ushort*)alloc((size_t)40 * NW * 8 * 2);      // k-major
    ushort* Ufp   = (ushort*)alloc((size_t)40 * KP * 8 * 2);      // k-major
    ushort* WzU   = (ushort*)alloc((size_t)3 * 40 * KP * 8 * 2);  // k-major
    ushort* Xall  = (ushort*)alloc((size_t)40 * MTOT * 8 * 2);    // k-major
    ushort* ZW    = (ushort*)alloc((size_t)MTOT * NW * 2);        // row-major
    ushort* FPbf  = (ushort*)alloc((size_t)NN * KP * 2);          // row-major
    ushort* HTp   = (ushort*)alloc((size_t)40 * NN * 8 * 2);      // k-major
    ushort* Hbf   = (ushort*)alloc((size_t)NN * KP * 2);          // row-major
    ushort* Hk    = (ushort*)alloc((size_t)40 * NN * 8 * 2);      // k-major
    float*  SCb   = (float*) alloc((size_t)NN * KP * 4);
    float*  C0    = (float*) alloc((size_t)NN * HH * 4);
    float*  BZ    = (float*) alloc(3 * KP * 4);
    float*  Bwf   = (float*) alloc(KP * 4);
    float*  BUFb  = (float*) alloc(KP * 4);

    pack_and_stage<<<11207, 256, 0, stream>>>(
        w_i, b_wi, u_i, b_ui, w_f, b_wf, u_f, b_uf,
        w_o, b_wo, u_o, b_uo, w_u, b_wu, u_u, b_uu,
        W4, Ufp, WzU, BZ, Bwf, BUFb, Hk,
        word_ids, emb, Xall);
    zx_all_kernel<<<7680, 256, 0, stream>>>(Xall, W4, Bwf, ZW);

    float* h_final = (float*)d_out;
    float* c_final = (float*)d_out + (size_t)NN * HH;

    for (int lev = 0; lev < LVLS; ++lev) {
        const int*    cidx  = child_idx  + (size_t)lev * NN * KK;
        const float*  cmask = child_mask + (size_t)lev * NN * KK;
        const ushort* ZWlev = ZW + (size_t)lev * NN * NW;
        const bool last = (lev == LVLS - 1);
        float* cdst = last ? c_final : C0;
        float* hdst = last ? h_final : nullptr;

        if (lev > 0)
            fp_kernel<<<640, 256, 0, stream>>>(Hk, Ufp, BUFb, FPbf);
        reduce_kernel<<<1024, dim3(80, 4), 0, stream>>>(
            Hbf, C0, FPbf, ZWlev, cidx, cmask, HTp, SCb);
        zgemm<<<640, 256, 0, stream>>>(
            HTp, WzU, BZ, SCb, ZWlev, cdst, Hbf, Hk, hdst);
    }
}

// Round 9
// 477.513 us; speedup vs baseline: 1.3788x; 1.0087x over previous
//
#include <hip/hip_runtime.h>
#include <cmath>
#include <cstdint>

// ---------------------------------------------------------------------------
// DependencyTreeLSTM (R9).  Lesson history:
//  R1 persistent grid-barrier: XCD L2 invalidates -> 2.8x regression.
//  R2 fused level kernel: 256-block grid cap -> latency-bound.
//  R3-R6: GEMMs invariant ~40us across schedules: UNCOALESCED STAGING
//     (lane->row at 640B stride = 64 lines per wave-load) was the defect.
//  R7: k-chunk-major global layouts (coalesced global_load_lds): 652->513.
//  R8: hoist X-half gates GEMM (ZW, prologue) + coalesced fp: 513->481.
//     zx_all now top kernel: 78us @ 516 TF, MfmaUtil 22% -- thin 128x64
//     tile (16 MFMA per 12 ds_reads).
//  R9: zx_all -> 128x128 tile, BK=32, 10-step dbuf + counted vmcnt(4)
//     (m97-structure: 16 MFMA per 8 ds_reads, 2x FLOP per staged byte).
//     Grid 3840.  Everything else frozen.
// ---------------------------------------------------------------------------

#define NN    4096
#define HH    300
#define KK    8
#define LVLS  12
#define KP    320
#define MTOT  49152   // 12*4096 rows in Xall
#define NW    1280    // ZW columns: [wf|wi|wo|wu]

typedef __bf16  bf16x8 __attribute__((ext_vector_type(8)));
typedef float   f32x4  __attribute__((ext_vector_type(4)));

#define GAS __attribute__((address_space(1)))
#define LAS __attribute__((address_space(3)))

__device__ __forceinline__ float sigmoidf_(float x) {
    return 1.0f / (1.0f + expf(-x));
}
__device__ __forceinline__ ushort f2bf(float f) {   // f32 -> bf16, RNE
    union { float f; uint32_t u; } v; v.f = f;
    return (ushort)((v.u + 0x7fffu + ((v.u >> 16) & 1u)) >> 16);
}
__device__ __forceinline__ float bf2f(ushort u) {
    union { uint32_t u; float f; } v; v.u = ((uint32_t)u) << 16;
    return v.f;
}

// ---------------------------------------------------------------------------
// pack (blocks [0,3527)) + stage X' (blocks [3527, 11207)).
// Layouts (all k-chunk-major = [k/8][cols][8], coalesced staging):
//   W4  [40][1280][8]   rows: 0-319 wf, 320-639 wi, 640-959 wo, 960-1279 wu
//   Uf' [40][320][8]
//   WzU [3][40][320][8] u_i / u_o / u_u
//   Xall'[40][49152][8]
//   BZ[3][320]=b_w+b_u (i,o,u), Bwf[320], BUF[320]
//   H'  [40][4096][8]: zero the k-pad elems (k>=300) once here.
// ---------------------------------------------------------------------------
__global__ __launch_bounds__(256)
void pack_and_stage(
    const float* __restrict__ wi, const float* __restrict__ bwi,
    const float* __restrict__ ui, const float* __restrict__ bui,
    const float* __restrict__ wf, const float* __restrict__ bwf,
    const float* __restrict__ uf, const float* __restrict__ buf_,
    const float* __restrict__ wo, const float* __restrict__ bwo,
    const float* __restrict__ uo, const float* __restrict__ buo,
    const float* __restrict__ wu, const float* __restrict__ bwu,
    const float* __restrict__ uu, const float* __restrict__ buu,
    ushort* __restrict__ W4, ushort* __restrict__ Ufp, ushort* __restrict__ WzU,
    float* __restrict__ BZ, float* __restrict__ Bwf, float* __restrict__ BUF,
    ushort* __restrict__ Hk,
    const int* __restrict__ word_ids, const float* __restrict__ emb,
    ushort* __restrict__ X)
{
    const int b = blockIdx.x;
    if (b >= 3527) {                                     // ---- stage X' ----
        int idx = (b - 3527) * 256 + threadIdx.x;        // 40 * 49152
        int kb = idx / MTOT, row = idx % MTOT;
        const int k0 = kb * 8;
        ushort o[8];
        if (kb < 37) {
            const float4* p = reinterpret_cast<const float4*>(
                emb + (size_t)word_ids[row] * 300 + k0);
            float4 v0 = p[0], v1 = p[1];
            o[0] = f2bf(v0.x); o[1] = f2bf(v0.y); o[2] = f2bf(v0.z); o[3] = f2bf(v0.w);
            o[4] = f2bf(v1.x); o[5] = f2bf(v1.y); o[6] = f2bf(v1.z); o[7] = f2bf(v1.w);
        } else if (kb == 37) {
            const float4 v0 = *reinterpret_cast<const float4*>(
                emb + (size_t)word_ids[row] * 300 + k0);
            o[0] = f2bf(v0.x); o[1] = f2bf(v0.y); o[2] = f2bf(v0.z); o[3] = f2bf(v0.w);
            o[4] = o[5] = o[6] = o[7] = 0;
        } else {
            o[0] = o[1] = o[2] = o[3] = o[4] = o[5] = o[6] = o[7] = 0;
        }
        ushort* dst = X + ((size_t)kb * MTOT + row) * 8;
        ushort4 a; a.x = o[0]; a.y = o[1]; a.z = o[2]; a.w = o[3];
        ushort4 c; c.x = o[4]; c.y = o[5]; c.z = o[6]; c.w = o[7];
        *reinterpret_cast<ushort4*>(dst)     = a;
        *reinterpret_cast<ushort4*>(dst + 4) = c;
        return;
    }
    int t = b * 256 + threadIdx.x;                       // ---- pack part ----
    if (t < 409600) {                                    // W4 [40][1280][8]
        int gate = t / 102400, rem = t % 102400;
        int r = rem / 320, k = rem % 320;
        const float* W = (gate == 0) ? wf : (gate == 1) ? wi
                       : (gate == 2) ? wo : wu;
        float v = (r < 300 && k < 300) ? W[r * 300 + k] : 0.f;
        W4[((size_t)(k >> 3) * NW + gate * 320 + r) * 8 + (k & 7)] = f2bf(v);
    } else if (t < 512000) {                             // Uf' [40][320][8]
        int x = t - 409600, r = x / 320, k = x % 320;
        Ufp[((size_t)(k >> 3) * KP + r) * 8 + (k & 7)] =
            f2bf((r < 300 && k < 300) ? uf[r * 300 + k] : 0.f);
    } else if (t < 819200) {                             // WzU [3][40][320][8]
        int x = t - 512000;
        int g = x / 102400, rem = x % 102400;
        int r = rem / 320, k = rem % 320;
        const float* U = (g == 0) ? ui : (g == 1) ? uo : uu;
        WzU[(((size_t)g * 40 + (k >> 3)) * KP + r) * 8 + (k & 7)] =
            f2bf((r < 300 && k < 300) ? U[r * 300 + k] : 0.f);
    } else if (t < 820160) {                             // BZ [3][320]
        int x = t - 819200, g = x / KP, r = x % KP;
        const float* bw = (g == 0) ? bwi : (g == 1) ? bwo : bwu;
        const float* bu = (g == 0) ? bui : (g == 1) ? buo : buu;
        BZ[x] = (r < 300) ? bw[r] + bu[r] : 0.f;
    } else if (t < 820480) {                             // Bwf
        int r = t - 820160;
        Bwf[r] = (r < 300) ? bwf[r] : 0.f;
    } else if (t < 820800) {                             // BUF
        int r = t - 820480;
        BUF[r] = (r < 300) ? buf_[r] : 0.f;
    } else if (t < 902720) {                             // H' k-pads -> 0
        int x = t - 820800;                              // 4096 * 20
        int row = x / 20, pe = x % 20;
        int k = 300 + pe;
        Hk[((size_t)(k >> 3) * NN + row) * 8 + (k & 7)] = 0;
    }
}

// ---------------------------------------------------------------------------
// ZW = X_all @ W4^T (+b_wf on cols<320) -> bf16 [49152][1280].
// Grid 3840 (384 m x 10 n), 256 thr, 128x128 tile (m97 structure: 16 MFMA
// per 8 ds_reads), BK=32, 10-step dbuf, counted vmcnt(4).  LDS 32 KB ->
// 4 blocks/CU.  Cols 0-319 = WXF (reduce); 320+g*320 = X-half of gate g.
// ---------------------------------------------------------------------------
__global__ __launch_bounds__(256)
void zx_all_kernel(const ushort* __restrict__ Xp, const ushort* __restrict__ W4,
                   const float* __restrict__ Bwf, ushort* __restrict__ ZW)
{
    __shared__ __attribute__((aligned(16))) ushort As[2][4][128][8];  // 16 KB
    __shared__ __attribute__((aligned(16))) ushort Bs[2][4][128][8];  // 16 KB

    const int b  = blockIdx.x;
    const int bj = (b % 8) * 480 + b / 8;         // bijective (3840 % 8 == 0)
    const int m0 = (bj / 10) * 128, n0 = (bj % 10) * 128;

    const int t = threadIdx.x, l = t & 63, w = t >> 6;
    const int m_off = (w >> 1) * 64, n_off = (w & 1) * 64;
    const int kq = l >> 4, lr = l & 15;

    f32x4 acc[4][4] = {};

    auto STAGE = [&](int buf, int s) {
        #pragma unroll
        for (int c = 0; c < 2; ++c) {             // A: 512 slots, 2/thread
            const int slot = t + 256 * c;
            const int kb = slot >> 7, row = slot & 127;
            const ushort* src = Xp + ((size_t)(s * 4 + kb) * MTOT + m0 + row) * 8;
            __builtin_amdgcn_global_load_lds((const GAS void*)src,
                (LAS void*)&As[buf][kb][row][0], 16, 0, 0);
        }
        #pragma unroll
        for (int c = 0; c < 2; ++c) {             // B: 512 slots, 2/thread
            const int slot = t + 256 * c;
            const int kb = slot >> 7, row = slot & 127;
            const ushort* src = W4 + ((size_t)(s * 4 + kb) * NW + n0 + row) * 8;
            __builtin_amdgcn_global_load_lds((const GAS void*)src,
                (LAS void*)&Bs[buf][kb][row][0], 16, 0, 0);
        }
    };
    auto COMPUTE = [&](int buf) {
        bf16x8 af[4], bfr[4];
        #pragma unroll
        for (int mi = 0; mi < 4; ++mi)
            af[mi] = *reinterpret_cast<const bf16x8*>(
                &As[buf][kq][m_off + mi * 16 + lr][0]);
        #pragma unroll
        for (int ni = 0; ni < 4; ++ni)
            bfr[ni] = *reinterpret_cast<const bf16x8*>(
                &Bs[buf][kq][n_off + ni * 16 + lr][0]);
        #pragma unroll
        for (int mi = 0; mi < 4; ++mi)
            #pragma unroll
            for (int ni = 0; ni < 4; ++ni)
                acc[mi][ni] = __builtin_amdgcn_mfma_f32_16x16x32_bf16(
                    af[mi], bfr[ni], acc[mi][ni], 0, 0, 0);
    };

    STAGE(0, 0);
    #pragma unroll
    for (int s = 0; s < 9; ++s) {
        STAGE((s + 1) & 1, s + 1);                // 4 loads in flight
        asm volatile("s_waitcnt vmcnt(4)" ::: "memory");
        __builtin_amdgcn_s_barrier();
        COMPUTE(s & 1);
        __builtin_amdgcn_s_barrier();
    }
    asm volatile("s_waitcnt vmcnt(0)" ::: "memory");
    __builtin_amdgcn_s_barrier();
    COMPUTE(1);                                   // step 9 -> buf 1

    const int col = l & 15, r0 = (l >> 4) * 4;
    #pragma unroll
    for (int mi = 0; mi < 4; ++mi) {
        #pragma unroll
        for (int ni = 0; ni < 4; ++ni) {
            const int gn = n0 + n_off + ni * 16 + col;
            const float bb = (gn < 320) ? Bwf[gn] : 0.f;
            #pragma unroll
            for (int r = 0; r < 4; ++r) {
                const int gm = m0 + m_off + mi * 16 + r0 + r;
                ZW[(size_t)gm * NW + gn] = f2bf(acc[mi][ni][r] + bb);
            }
        }
    }
}

// ---------------------------------------------------------------------------
// FP = H @ u_f^T + b_uf -> bf16 [4096][320] row-major.  Coalesced staged
// dbuf GEMM: A = H' k-major (written by zgemm), B = Uf' k-major.
// Grid 640 (64 m x 10 j), 256 thr, tile 64x32, BK=64, 5 steps, vmcnt(3).
// ---------------------------------------------------------------------------
__global__ __launch_bounds__(256)
void fp_kernel(const ushort* __restrict__ Hk, const ushort* __restrict__ Ufp,
               const float* __restrict__ BUFb, ushort* __restrict__ FP)
{
    __shared__ __attribute__((aligned(16))) ushort As[2][8][64][8];   // 16 KB
    __shared__ __attribute__((aligned(16))) ushort Bs[2][8][32][8];   //  8 KB

    const int b  = blockIdx.x;
    const int bj = (b % 8) * 80 + b / 8;          // bijective (640 % 8 == 0)
    const int m0 = (bj / 10) * 64, j0 = (bj % 10) * 32;

    const int t = threadIdx.x, w = t >> 6, l = t & 63;
    const int kq = l >> 4, lr = l & 15;
    const int m_off = (w >> 1) * 32, j_off = (w & 1) * 16;

    f32x4 acc[2] = {};

    auto STAGE = [&](int buf, int s) {
        #pragma unroll
        for (int c = 0; c < 2; ++c) {             // A: 512 slots, 2/thread
            const int slot = t + 256 * c;
            const int kb = slot >> 6, row = slot & 63;
            const ushort* src = Hk + ((size_t)(s * 8 + kb) * NN + m0 + row) * 8;
            __builtin_amdgcn_global_load_lds((const GAS void*)src,
                (LAS void*)&As[buf][kb][row][0], 16, 0, 0);
        }
        {                                         // B: 256 slots, 1/thread
            const int kb = t >> 5, row = t & 31;
            const ushort* src = Ufp + ((size_t)(s * 8 + kb) * KP + j0 + row) * 8;
            __builtin_amdgcn_global_load_lds((const GAS void*)src,
                (LAS void*)&Bs[buf][kb][row][0], 16, 0, 0);
        }
    };
    auto COMPUTE = [&](int buf) {
        #pragma unroll
        for (int kk = 0; kk < 2; ++kk) {
            const int kc = kk * 4 + kq;
            bf16x8 af[2], bf;
            #pragma unroll
            for (int mi = 0; mi < 2; ++mi)
                af[mi] = *reinterpret_cast<const bf16x8*>(
                    &As[buf][kc][m_off + mi * 16 + lr][0]);
            bf = *reinterpret_cast<const bf16x8*>(
                    &Bs[buf][kc][j_off + lr][0]);
            #pragma unroll
            for (int mi = 0; mi < 2; ++mi)
                acc[mi] = __builtin_amdgcn_mfma_f32_16x16x32_bf16(
                    af[mi], bf, acc[mi], 0, 0, 0);
        }
    };

    STAGE(0, 0);
    #pragma unroll
    for (int s = 0; s < 4; ++s) {
        STAGE((s + 1) & 1, s + 1);                // 3 loads in flight
        asm volatile("s_waitcnt vmcnt(3)" ::: "memory");
        __builtin_amdgcn_s_barrier();
        COMPUTE(s & 1);
        __builtin_amdgcn_s_barrier();
    }
    asm volatile("s_waitcnt vmcnt(0)" ::: "memory");
    __builtin_amdgcn_s_barrier();
    COMPUTE(0);                                   // step 4 -> buf 0

    const int col = l & 15, r0 = (l >> 4) * 4;
    const int gn = j0 + j_off + col;
    if (gn < 300) {
        const float bb = BUFb[gn];
        #pragma unroll
        for (int mi = 0; mi < 2; ++mi)
            #pragma unroll
            for (int r = 0; r < 4; ++r)
                FP[(size_t)(m0 + m_off + mi * 16 + r0 + r) * KP + gn] =
                    f2bf(acc[mi][r] + bb);
    }
}

// ---------------------------------------------------------------------------
// Child gather + masked sums.  4 nodes/block, branchless prefetched loads.
// WXF = ZW cols 0-319 (stride NW).  HT written k-chunk-major + pads zeroed.
// ---------------------------------------------------------------------------
__global__ __launch_bounds__(320)
void reduce_kernel(const ushort* __restrict__ Hbf, const float* __restrict__ Cst,
                   const ushort* __restrict__ FP, const ushort* __restrict__ ZWlev,
                   const int* __restrict__ cidx, const float* __restrict__ cmask,
                   ushort* __restrict__ HTp, float* __restrict__ SC)
{
    const int x = threadIdx.x;          // 0..79
    const int ty = threadIdx.y;         // 0..3
    const int n = blockIdx.x * 4 + ty;
    __shared__ int   ch[4][KK];
    __shared__ float mk[4][KK];
    if (x < KK) {
        ch[ty][x] = cidx[n * KK + x];
        mk[ty][x] = cmask[n * KK + x];
    }
    __syncthreads();
    if (x >= 75) {                      // zero HT' k-pad chunks
        ushort4 z; z.x = z.y = z.z = z.w = 0;
        const int pi = x - 75;          // (37,4),(38,0),(38,4),(39,0),(39,4)
        const int kb = 37 + ((pi + 1) >> 1);
        const int off = ((pi & 1) ^ 1) * 4;
        *reinterpret_cast<ushort4*>(
            HTp + ((size_t)kb * NN + n) * 8 + off) = z;
        return;
    }
    const int h = x * 4;

    ushort4 hu[KK]; ushort4 fu[KK]; float4 cv[KK];
    #pragma unroll
    for (int k = 0; k < KK; ++k) {
        const size_t cr = (size_t)ch[ty][k];
        hu[k] = *reinterpret_cast<const ushort4*>(&Hbf[cr * KP + h]);
        fu[k] = *reinterpret_cast<const ushort4*>(&FP [cr * KP + h]);
        cv[k] = *reinterpret_cast<const float4*>(&Cst[cr * HH + h]);
    }

    ushort4 wxu = *reinterpret_cast<const ushort4*>(&ZWlev[(size_t)n * NW + h]);
    const float wx0 = bf2f(wxu.x), wx1 = bf2f(wxu.y),
                wx2 = bf2f(wxu.z), wx3 = bf2f(wxu.w);
    float ht0 = 0.f, ht1 = 0.f, ht2 = 0.f, ht3 = 0.f;
    float sc0 = 0.f, sc1 = 0.f, sc2 = 0.f, sc3 = 0.f;

    #pragma unroll
    for (int k = 0; k < KK; ++k) {
        const float m = mk[ty][k];
        if (m != 0.f) {
            ht0 += m * bf2f(hu[k].x); ht1 += m * bf2f(hu[k].y);
            ht2 += m * bf2f(hu[k].z); ht3 += m * bf2f(hu[k].w);
            sc0 += m * sigmoidf_(wx0 + bf2f(fu[k].x)) * cv[k].x;
            sc1 += m * sigmoidf_(wx1 + bf2f(fu[k].y)) * cv[k].y;
            sc2 += m * sigmoidf_(wx2 + bf2f(fu[k].z)) * cv[k].z;
            sc3 += m * sigmoidf_(wx3 + bf2f(fu[k].w)) * cv[k].w;
        }
    }
    ushort4 ho; ho.x = f2bf(ht0); ho.y = f2bf(ht1); ho.z = f2bf(ht2); ho.w = f2bf(ht3);
    *reinterpret_cast<ushort4*>(
        HTp + ((size_t)(x >> 1) * NN + n) * 8 + (x & 1) * 4) = ho;
    float4 so; so.x = sc0; so.y = sc1; so.z = sc2; so.w = sc3;
    *reinterpret_cast<float4*>(&SC[(size_t)n * KP + h]) = so;
}

// ---------------------------------------------------------------------------
// zgemm: HT-half gates GEMM (K=320, 5 steps) + X-half addend from ZW +
// fused cell epilogue.  A = HT' k-major, B = WzU k-major.  Tile 64r x 32j x
// 3 gates; grid 640, 256 thr; dbuf, vmcnt(5).  Writes C, H row-major (for
// reduce gather) and H' k-major (for next level's fp staging).
// ---------------------------------------------------------------------------
__global__ __launch_bounds__(256)
void zgemm(const ushort* __restrict__ HTp, const ushort* __restrict__ WzU,
           const float* __restrict__ BZ, const float* __restrict__ SC,
           const ushort* __restrict__ ZXlev,
           float* __restrict__ cdst, ushort* __restrict__ Hb,
           ushort* __restrict__ Hk, float* __restrict__ hdst)
{
    __shared__ __attribute__((aligned(16))) ushort As[2][8][64][8];    // 16 KB
    __shared__ __attribute__((aligned(16))) ushort Bs[2][3][8][32][8]; // 24 KB

    const int b  = blockIdx.x;
    const int bj = (b % 8) * 80 + b / 8;          // bijective (640 % 8 == 0)
    const int m0 = (bj / 10) * 64, j0 = (bj % 10) * 32;

    const int t = threadIdx.x, w = t >> 6, l = t & 63;
    const int kq = l >> 4, lr = l & 15;
    const int m_off = (w >> 1) * 32, j_off = (w & 1) * 16;

    f32x4 acc[3][2] = {};

    auto STAGE = [&](int buf, int s) {
        #pragma unroll
        for (int c = 0; c < 2; ++c) {             // A: 512 slots, 2/thread
            const int slot = t + 256 * c;
            const int kb = slot >> 6, row = slot & 63;
            const ushort* src = HTp + ((size_t)(s * 8 + kb) * NN + m0 + row) * 8;
            __builtin_amdgcn_global_load_lds((const GAS void*)src,
                (LAS void*)&As[buf][kb][row][0], 16, 0, 0);
        }
        #pragma unroll
        for (int c = 0; c < 3; ++c) {             // B: 768 slots, 3/thread
            const int slot = t + 256 * c;
            const int g = slot >> 8, rem = slot & 255;
            const int kb = rem >> 5, row = rem & 31;
            const ushort* src = WzU +
                (((size_t)g * 40 + s * 8 + kb) * KP + j0 + row) * 8;
            __builtin_amdgcn_global_load_lds((const GAS void*)src,
                (LAS void*)&Bs[buf][g][kb][row][0], 16, 0, 0);
        }
    };
    auto COMPUTE = [&](int buf) {
        #pragma unroll
        for (int kk = 0; kk < 2; ++kk) {
            const int kc = kk * 4 + kq;
            bf16x8 af[2], bfr[3];
            #pragma unroll
            for (int mi = 0; mi < 2; ++mi)
                af[mi] = *reinterpret_cast<const bf16x8*>(
                    &As[buf][kc][m_off + mi * 16 + lr][0]);
            #pragma unroll
            for (int g = 0; g < 3; ++g)
                bfr[g] = *reinterpret_cast<const bf16x8*>(
                    &Bs[buf][g][kc][j_off + lr][0]);
            #pragma unroll
            for (int g = 0; g < 3; ++g)
                #pragma unroll
                for (int mi = 0; mi < 2; ++mi)
                    acc[g][mi] = __builtin_amdgcn_mfma_f32_16x16x32_bf16(
                        af[mi], bfr[g], acc[g][mi], 0, 0, 0);
        }
    };

    STAGE(0, 0);
    #pragma unroll
    for (int s = 0; s < 4; ++s) {
        STAGE((s + 1) & 1, s + 1);                // 5 loads in flight
        asm volatile("s_waitcnt vmcnt(5)" ::: "memory");
        __builtin_amdgcn_s_barrier();
        COMPUTE(s & 1);
        __builtin_amdgcn_s_barrier();
    }
    asm volatile("s_waitcnt vmcnt(0)" ::: "memory");
    __builtin_amdgcn_s_barrier();
    COMPUTE(0);                                   // step 4 -> buf 0

    // ---- epilogue: + X-half (ZW) + bias -> cell update ------------------
    const int col = l & 15, r0 = (l >> 4) * 4;
    const int gn = j0 + j_off + col;
    if (gn < 300) {
        const float bi_ = BZ[gn], bo_ = BZ[KP + gn], bu_ = BZ[2 * KP + gn];
        #pragma unroll
        for (int mi = 0; mi < 2; ++mi) {
            #pragma unroll
            for (int r = 0; r < 4; ++r) {
                const int gm = m0 + m_off + mi * 16 + r0 + r;
                const size_t zb = (size_t)gm * NW + 320 + gn;
                const float zi = bf2f(ZXlev[zb]);
                const float zo = bf2f(ZXlev[zb + 320]);
                const float zu = bf2f(ZXlev[zb + 640]);
                const float sc = SC[(size_t)gm * KP + gn];
                const float ig = sigmoidf_(acc[0][mi][r] + zi + bi_);
                const float og = sigmoidf_(acc[1][mi][r] + zo + bo_);
                const float ug = tanhf   (acc[2][mi][r] + zu + bu_);
                const float c  = ig * ug + sc;
                const float hv = og * tanhf(c);
                cdst[(size_t)gm * HH + gn] = c;
                const ushort hb = f2bf(hv);
                Hb[(size_t)gm * KP + gn] = hb;
                Hk[((size_t)(gn >> 3) * NN + gm) * 8 + (gn & 7)] = hb;
                if (hdst) hdst[(size_t)gm * HH + gn] = hv;
            }
        }
    }
}

// ---------------------------------------------------------------------------
extern "C" void kernel_launch(void* const* d_in, const int* in_sizes, int n_in,
                              void* d_out, int out_size, void* d_ws, size_t ws_size,
                              hipStream_t stream)
{
    const int*   word_ids   = (const int*)  d_in[0];
    const int*   child_idx  = (const int*)  d_in[1];
    const float* child_mask = (const float*)d_in[2];
    const float* emb        = (const float*)d_in[3];
    const float* w_i  = (const float*)d_in[4];  const float* b_wi = (const float*)d_in[5];
    const float* u_i  = (const float*)d_in[6];  const float* b_ui = (const float*)d_in[7];
    const float* w_f  = (const float*)d_in[8];  const float* b_wf = (const float*)d_in[9];
    const float* u_f  = (const float*)d_in[10]; const float* b_uf = (const float*)d_in[11];
    const float* w_o  = (const float*)d_in[12]; const float* b_wo = (const float*)d_in[13];
    const float* u_o  = (const float*)d_in[14]; const float* b_uo = (const float*)d_in[15];
    const float* w_u  = (const float*)d_in[16]; const float* b_wu = (const float*)d_in[17];
    const float* u_u  = (const float*)d_in[18]; const float* b_uu = (const float*)d_in[19];

    uint8_t* ws = (uint8_t*)d_ws;
    size_t off = 0;
    auto alloc = [&](size_t bytes) {
        uint8_t* p = ws + off;
        off += (bytes + 255) & ~(size_t)255;
        return p;
    };
    ushort* W4    = (ushort*)alloc((size_t)40 * NW * 8 * 2);      // k-major
    ushort* Ufp   = (ushort*)alloc((size_t)40 * KP * 8 * 2);      // k-major
    ushort* WzU   = (ushort*)alloc((size_t)3 * 40 * KP * 8 * 2);  // k-major
    ushort* Xall  = (ushort*)alloc((size_t)40 * MTOT * 8 * 2);    // k-major
    ushort* ZW    = (ushort*)alloc((size_t)MTOT * NW * 2);        // row-major
    ushort* FPbf  = (ushort*)alloc((size_t)NN * KP * 2);          // row-major
    ushort* HTp   = (ushort*)alloc((size_t)40 * NN * 8 * 2);      // k-major
    ushort* Hbf   = (ushort*)alloc((size_t)NN * KP * 2);          // row-major
    ushort* Hk    = (ushort*)alloc((size_t)40 * NN * 8 * 2);      // k-major
    float*  SCb   = (float*) alloc((size_t)NN * KP * 4);
    float*  C0    = (float*) alloc((size_t)NN * HH * 4);
    float*  BZ    = (float*) alloc(3 * KP * 4);
    float*  Bwf   = (float*) alloc(KP * 4);
    float*  BUFb  = (float*) alloc(KP * 4);

    pack_and_stage<<<11207, 256, 0, stream>>>(
        w_i, b_wi, u_i, b_ui, w_f, b_wf, u_f, b_uf,
        w_o, b_wo, u_o, b_uo, w_u, b_wu, u_u, b_uu,
        W4, Ufp, WzU, BZ, Bwf, BUFb, Hk,
        word_ids, emb, Xall);
    zx_all_kernel<<<3840, 256, 0, stream>>>(Xall, W4, Bwf, ZW);

    float* h_final = (float*)d_out;
    float* c_final = (float*)d_out + (size_t)NN * HH;

    for (int lev = 0; lev < LVLS; ++lev) {
        const int*    cidx  = child_idx  + (size_t)lev * NN * KK;
        const float*  cmask = child_mask + (size_t)lev * NN * KK;
        const ushort* ZWlev = ZW + (size_t)lev * NN * NW;
        const bool last = (lev == LVLS - 1);
        float* cdst = last ? c_final : C0;
        float* hdst = last ? h_final : nullptr;

        if (lev > 0)
            fp_kernel<<<640, 256, 0, stream>>>(Hk, Ufp, BUFb, FPbf);
        reduce_kernel<<<1024, dim3(80, 4), 0, stream>>>(
            Hbf, C0, FPbf, ZWlev, cidx, cmask, HTp, SCb);
        zgemm<<<640, 256, 0, stream>>>(
            HTp, WzU, BZ, SCb, ZWlev, cdst, Hbf, Hk, hdst);
    }
}